// Round 1
// baseline (369.839 us; speedup 1.0000x reference)
//
#include <hip/hip_runtime.h>
#include <hip/hip_bf16.h>
#include <stdint.h>
#include <stddef.h>

typedef short short8 __attribute__((ext_vector_type(8)));
typedef float f32x4 __attribute__((ext_vector_type(4)));

#define SROWS 65536
#define TROWS 8192
#define HDIM  1024
#define KDIM  2048   // concatenated K: [edu | h]
#define NDIM  4096   // c = 4*j + gate

__device__ __forceinline__ unsigned short f2bf(float f) {
  union { float f; uint32_t u; } v; v.f = f;
  uint32_t u = v.u;
  uint32_t r = (u + 0x7FFFu + ((u >> 16) & 1u)) >> 16;
  return (unsigned short)r;
}

__device__ __forceinline__ float fast_sigmoid(float x) {
  return __builtin_amdgcn_rcpf(1.0f + __builtin_amdgcn_exp2f(-1.44269504f * x));
}
__device__ __forceinline__ float fast_tanh(float x) {
  // 1 - 2/(1+e^{2x}) : saturates correctly at both ends, no inf-inf
  return 1.0f - 2.0f * __builtin_amdgcn_rcpf(1.0f + __builtin_amdgcn_exp2f(2.88539008f * x));
}

// ---------------- small prep kernels ----------------

__global__ __launch_bounds__(256) void k_initlp(int* lp) {
  int i = blockIdx.x * 256 + threadIdx.x;
  if (i < SROWS) lp[i] = -1;
}

__global__ __launch_bounds__(256) void k_lp(const int* __restrict__ sid, int* lp) {
  int i = blockIdx.x * 256 + threadIdx.x;
  if (i < TROWS) atomicMax(&lp[sid[i]], i);
}

__global__ __launch_bounds__(256) void k_bias(const float* __restrict__ bih,
                                              const float* __restrict__ bhh,
                                              float* __restrict__ btab) {
  int j = blockIdx.x * 256 + threadIdx.x;
  if (j < HDIM) {
    btab[4*j+0] = bih[j] + bhh[j];
    btab[4*j+1] = bih[j+HDIM] + bhh[j+HDIM];
    btab[4*j+2] = bih[j+2*HDIM];
    btab[4*j+3] = bhh[j+2*HDIM];
  }
}

// Ac[t][k] bf16: k<1024 -> edu[t][k]; else mem[sid[t]][k-1024]
__global__ __launch_bounds__(256) void k_build_A(const float* __restrict__ edu,
                                                 const float* __restrict__ mem,
                                                 const int* __restrict__ sid,
                                                 unsigned short* __restrict__ Ac) {
  const int idx = blockIdx.x * 256 + threadIdx.x;   // 2,097,152 chunks of 8
  const int t  = idx >> 8;
  const int k0 = (idx & 255) << 3;
  const float* src;
  if (k0 < HDIM) src = edu + (size_t)t * HDIM + k0;
  else           src = mem + (size_t)sid[t] * HDIM + (k0 - HDIM);
  f32x4 f0 = *(const f32x4*)src;
  f32x4 f1 = *(const f32x4*)(src + 4);
  short8 v;
  v[0]=(short)f2bf(f0[0]); v[1]=(short)f2bf(f0[1]); v[2]=(short)f2bf(f0[2]); v[3]=(short)f2bf(f0[3]);
  v[4]=(short)f2bf(f1[0]); v[5]=(short)f2bf(f1[1]); v[6]=(short)f2bf(f1[2]); v[7]=(short)f2bf(f1[3]);
  *(short8*)(Ac + (size_t)idx * 8) = v;
}

// Bc[c][k] bf16, c = 4*j + g:
//  g0: [Wih[j] | Whh[j]]   g1: [Wih[j+H] | Whh[j+H]]
//  g2: [Wih[j+2H] | 0]     g3: [0 | Whh[j+2H]]
__global__ __launch_bounds__(256) void k_build_B(const float* __restrict__ Wih,
                                                 const float* __restrict__ Whh,
                                                 unsigned short* __restrict__ Bc) {
  const int idx = blockIdx.x * 256 + threadIdx.x;   // 1,048,576 chunks of 8
  const int c  = idx >> 8;
  const int k0 = (idx & 255) << 3;
  const int j  = c >> 2;
  const int g  = c & 3;
  const float* src = nullptr;
  if (g == 0)      src = (k0 < HDIM) ? Wih + (size_t)j * HDIM + k0
                                     : Whh + (size_t)j * HDIM + (k0 - HDIM);
  else if (g == 1) src = (k0 < HDIM) ? Wih + (size_t)(j + HDIM) * HDIM + k0
                                     : Whh + (size_t)(j + HDIM) * HDIM + (k0 - HDIM);
  else if (g == 2) { if (k0 < HDIM)  src = Wih + (size_t)(j + 2*HDIM) * HDIM + k0; }
  else             { if (k0 >= HDIM) src = Whh + (size_t)(j + 2*HDIM) * HDIM + (k0 - HDIM); }
  short8 v = (short8)0;
  if (src) {
    f32x4 f0 = *(const f32x4*)src;
    f32x4 f1 = *(const f32x4*)(src + 4);
    v[0]=(short)f2bf(f0[0]); v[1]=(short)f2bf(f0[1]); v[2]=(short)f2bf(f0[2]); v[3]=(short)f2bf(f0[3]);
    v[4]=(short)f2bf(f1[0]); v[5]=(short)f2bf(f1[1]); v[6]=(short)f2bf(f1[2]); v[7]=(short)f2bf(f1[3]);
  }
  *(short8*)(Bc + (size_t)idx * 8) = v;
}

// copy untouched rows
__global__ __launch_bounds__(256) void k_copy(const float* __restrict__ mem,
                                              const int* __restrict__ lp,
                                              float* __restrict__ out) {
  for (int s = blockIdx.x; s < SROWS; s += gridDim.x) {
    if (lp[s] >= 0) continue;
    const f32x4* src = (const f32x4*)(mem + (size_t)s * HDIM);
    f32x4* dst = (f32x4*)(out + (size_t)s * HDIM);
    dst[threadIdx.x] = src[threadIdx.x];
  }
}

// ---------------- fused GEMM + gates + scatter ----------------
// m97-style: 128x128 tile, BK=32, 4 waves (each 64x64), global_load_lds width 16.
// grid: (TROWS/128, NDIM/128) = (64, 32)

__global__ __launch_bounds__(256) void k_gru(const unsigned short* __restrict__ Ac,
                                             const unsigned short* __restrict__ Bc,
                                             const float* __restrict__ mem,
                                             const int* __restrict__ sid,
                                             const int* __restrict__ lp,
                                             const float* __restrict__ btab,
                                             float* __restrict__ out) {
  __shared__ __align__(16) char smraw[17408];
  unsigned short* As = (unsigned short*)smraw;           // [128][32]
  unsigned short* Bs = (unsigned short*)(smraw + 8192);  // [128][32]
  float* epi = (float*)smraw;                            // [4][16][68] (after K-loop)

  const int tid  = threadIdx.x;
  const int lane = tid & 63;
  const int w    = tid >> 6;
  const int t0   = blockIdx.x * 128;
  const int c0   = blockIdx.y * 128;
  const int wm   = (w >> 1) * 64;
  const int wn   = (w & 1) * 64;

  f32x4 acc[4][4];
#pragma unroll
  for (int i = 0; i < 4; i++)
#pragma unroll
    for (int j = 0; j < 4; j++) acc[i][j] = (f32x4){0.f, 0.f, 0.f, 0.f};

  // staging: wave w covers rows [w*32, w*32+32) of each 128x32 tile, 2 loads/matrix
  const int arow = w * 32 + (lane >> 2);
  const int acol = (lane & 3) * 8;
  const unsigned short* gA = Ac + (size_t)(t0 + arow) * KDIM + acol;
  const unsigned short* gB = Bc + (size_t)(c0 + arow) * KDIM + acol;
  unsigned short* lA = As + w * 1024;
  unsigned short* lB = Bs + w * 1024;

  const unsigned short* fA = As + (wm + (lane & 15)) * 32 + (lane >> 4) * 8;
  const unsigned short* fB = Bs + (wn + (lane & 15)) * 32 + (lane >> 4) * 8;

  for (int kk = 0; kk < KDIM; kk += 32) {
    __builtin_amdgcn_global_load_lds((const __attribute__((address_space(1))) void*)(gA + kk),
                                     (__attribute__((address_space(3))) void*)lA, 16, 0, 0);
    __builtin_amdgcn_global_load_lds((const __attribute__((address_space(1))) void*)(gA + 16 * KDIM + kk),
                                     (__attribute__((address_space(3))) void*)(lA + 512), 16, 0, 0);
    __builtin_amdgcn_global_load_lds((const __attribute__((address_space(1))) void*)(gB + kk),
                                     (__attribute__((address_space(3))) void*)lB, 16, 0, 0);
    __builtin_amdgcn_global_load_lds((const __attribute__((address_space(1))) void*)(gB + 16 * KDIM + kk),
                                     (__attribute__((address_space(3))) void*)(lB + 512), 16, 0, 0);
    __syncthreads();
    short8 a[4], b[4];
#pragma unroll
    for (int i = 0; i < 4; i++) a[i] = *(const short8*)(fA + i * 512);
#pragma unroll
    for (int i = 0; i < 4; i++) b[i] = *(const short8*)(fB + i * 512);
#pragma unroll
    for (int i = 0; i < 4; i++)
#pragma unroll
      for (int j = 0; j < 4; j++)
        acc[i][j] = __builtin_amdgcn_mfma_f32_16x16x32_bf16(a[i], b[j], acc[i][j], 0, 0, 0);
    __syncthreads();
  }

  // epilogue: per-wave LDS transpose chunk (16 rows x 64 c-cols), gates, scatter
  const int row    = lane & 15;
  const int jq     = lane >> 4;
  const int jfirst = ((c0 + wn) >> 2) + jq * 4;   // global j of this lane's 4 outputs

#pragma unroll
  for (int mf = 0; mf < 4; mf++) {
#pragma unroll
    for (int nf = 0; nf < 4; nf++)
#pragma unroll
      for (int r = 0; r < 4; r++)
        epi[w * (16 * 68) + ((lane >> 4) * 4 + r) * 68 + nf * 16 + (lane & 15)] = acc[mf][nf][r];
    __syncthreads();  // uniform; orders LDS writes vs reads (per-wave regions)

    const int trow = t0 + wm + mf * 16 + row;
    const int s    = sid[trow];
    const bool wr  = (lp[s] == trow);

    f32x4 q[4];
#pragma unroll
    for (int jj = 0; jj < 4; jj++)
      q[jj] = *(const f32x4*)&epi[w * (16 * 68) + row * 68 + jq * 16 + jj * 4];

    f32x4 hv = *(const f32x4*)&mem[(size_t)s * HDIM + jfirst];
    f32x4 o;
#pragma unroll
    for (int jj = 0; jj < 4; jj++) {
      const int j = jfirst + jj;
      f32x4 bt = *(const f32x4*)&btab[4 * j];
      float rr = fast_sigmoid(q[jj][0] + bt[0]);
      float zz = fast_sigmoid(q[jj][1] + bt[1]);
      float nn = fast_tanh(q[jj][2] + bt[2] + rr * (q[jj][3] + bt[3]));
      o[jj] = (1.0f - zz) * nn + zz * hv[jj];
    }
    if (wr) *(f32x4*)&out[(size_t)s * HDIM + jfirst] = o;
    __syncthreads();  // reads done before next chunk overwrites
  }
}

// ---------------- launch ----------------

extern "C" void kernel_launch(void* const* d_in, const int* in_sizes, int n_in,
                              void* d_out, int out_size, void* d_ws, size_t ws_size,
                              hipStream_t stream) {
  const float* mem = (const float*)d_in[0];
  const int*   sid = (const int*)d_in[1];
  const float* edu = (const float*)d_in[2];
  const float* Wih = (const float*)d_in[3];
  const float* Whh = (const float*)d_in[4];
  const float* bih = (const float*)d_in[5];
  const float* bhh = (const float*)d_in[6];
  float* out = (float*)d_out;

  char* p = (char*)d_ws;
  unsigned short* Ac = (unsigned short*)p; p += (size_t)TROWS * KDIM * 2;   // 32 MiB
  unsigned short* Bc = (unsigned short*)p; p += (size_t)NDIM * KDIM * 2;    // 16 MiB
  int*   lp   = (int*)p;   p += (size_t)SROWS * 4;                          // 256 KiB
  float* btab = (float*)p; p += (size_t)HDIM * 4 * 4;                       // 16 KiB

  hipLaunchKernelGGL(k_initlp, dim3(SROWS / 256), dim3(256), 0, stream, lp);
  hipLaunchKernelGGL(k_lp, dim3(TROWS / 256), dim3(256), 0, stream, sid, lp);
  hipLaunchKernelGGL(k_bias, dim3(4), dim3(256), 0, stream, bih, bhh, btab);
  hipLaunchKernelGGL(k_build_A, dim3((TROWS * KDIM / 8) / 256), dim3(256), 0, stream, edu, mem, sid, Ac);
  hipLaunchKernelGGL(k_build_B, dim3((NDIM * KDIM / 8) / 256), dim3(256), 0, stream, Wih, Whh, Bc);
  hipLaunchKernelGGL(k_copy, dim3(8192), dim3(256), 0, stream, mem, lp, out);
  hipLaunchKernelGGL(k_gru, dim3(TROWS / 128, NDIM / 128), dim3(256), 0, stream,
                     Ac, Bc, mem, sid, lp, btab, out);
}

// Round 2
// 274.121 us; speedup vs baseline: 1.3492x; 1.3492x over previous
//
#include <hip/hip_runtime.h>
#include <hip/hip_bf16.h>
#include <stdint.h>
#include <stddef.h>

typedef short short8 __attribute__((ext_vector_type(8)));
typedef float f32x4 __attribute__((ext_vector_type(4)));

#define SROWS 65536
#define TROWS 8192
#define HDIM  1024
#define KDIM  2048   // concatenated K: [edu | h]
#define NDIM  4096   // c = 4*j + gate
#define NT    (KDIM / 64)

__device__ __forceinline__ unsigned short f2bf(float f) {
  union { float f; uint32_t u; } v; v.f = f;
  uint32_t u = v.u;
  uint32_t r = (u + 0x7FFFu + ((u >> 16) & 1u)) >> 16;
  return (unsigned short)r;
}

__device__ __forceinline__ float fast_sigmoid(float x) {
  return __builtin_amdgcn_rcpf(1.0f + __builtin_amdgcn_exp2f(-1.44269504f * x));
}
__device__ __forceinline__ float fast_tanh(float x) {
  return 1.0f - 2.0f * __builtin_amdgcn_rcpf(1.0f + __builtin_amdgcn_exp2f(2.88539008f * x));
}

// ---------------- small prep kernels ----------------

__global__ __launch_bounds__(256) void k_initlp(int* lp) {
  int i = blockIdx.x * 256 + threadIdx.x;
  if (i < SROWS) lp[i] = -1;
}

__global__ __launch_bounds__(256) void k_lp(const int* __restrict__ sid, int* lp) {
  int i = blockIdx.x * 256 + threadIdx.x;
  if (i < TROWS) atomicMax(&lp[sid[i]], i);
}

__global__ __launch_bounds__(256) void k_bias(const float* __restrict__ bih,
                                              const float* __restrict__ bhh,
                                              float* __restrict__ btab) {
  int j = blockIdx.x * 256 + threadIdx.x;
  if (j < HDIM) {
    btab[4*j+0] = bih[j] + bhh[j];
    btab[4*j+1] = bih[j+HDIM] + bhh[j+HDIM];
    btab[4*j+2] = bih[j+2*HDIM];
    btab[4*j+3] = bhh[j+2*HDIM];
  }
}

__global__ __launch_bounds__(256) void k_build_A(const float* __restrict__ edu,
                                                 const float* __restrict__ mem,
                                                 const int* __restrict__ sid,
                                                 unsigned short* __restrict__ Ac) {
  const int idx = blockIdx.x * 256 + threadIdx.x;
  const int t  = idx >> 8;
  const int k0 = (idx & 255) << 3;
  const float* src;
  if (k0 < HDIM) src = edu + (size_t)t * HDIM + k0;
  else           src = mem + (size_t)sid[t] * HDIM + (k0 - HDIM);
  f32x4 f0 = *(const f32x4*)src;
  f32x4 f1 = *(const f32x4*)(src + 4);
  short8 v;
  v[0]=(short)f2bf(f0[0]); v[1]=(short)f2bf(f0[1]); v[2]=(short)f2bf(f0[2]); v[3]=(short)f2bf(f0[3]);
  v[4]=(short)f2bf(f1[0]); v[5]=(short)f2bf(f1[1]); v[6]=(short)f2bf(f1[2]); v[7]=(short)f2bf(f1[3]);
  *(short8*)(Ac + (size_t)idx * 8) = v;
}

__global__ __launch_bounds__(256) void k_build_B(const float* __restrict__ Wih,
                                                 const float* __restrict__ Whh,
                                                 unsigned short* __restrict__ Bc) {
  const int idx = blockIdx.x * 256 + threadIdx.x;
  const int c  = idx >> 8;
  const int k0 = (idx & 255) << 3;
  const int j  = c >> 2;
  const int g  = c & 3;
  const float* src = nullptr;
  if (g == 0)      src = (k0 < HDIM) ? Wih + (size_t)j * HDIM + k0
                                     : Whh + (size_t)j * HDIM + (k0 - HDIM);
  else if (g == 1) src = (k0 < HDIM) ? Wih + (size_t)(j + HDIM) * HDIM + k0
                                     : Whh + (size_t)(j + HDIM) * HDIM + (k0 - HDIM);
  else if (g == 2) { if (k0 < HDIM)  src = Wih + (size_t)(j + 2*HDIM) * HDIM + k0; }
  else             { if (k0 >= HDIM) src = Whh + (size_t)(j + 2*HDIM) * HDIM + (k0 - HDIM); }
  short8 v = (short8)0;
  if (src) {
    f32x4 f0 = *(const f32x4*)src;
    f32x4 f1 = *(const f32x4*)(src + 4);
    v[0]=(short)f2bf(f0[0]); v[1]=(short)f2bf(f0[1]); v[2]=(short)f2bf(f0[2]); v[3]=(short)f2bf(f0[3]);
    v[4]=(short)f2bf(f1[0]); v[5]=(short)f2bf(f1[1]); v[6]=(short)f2bf(f1[2]); v[7]=(short)f2bf(f1[3]);
  }
  *(short8*)(Bc + (size_t)idx * 8) = v;
}

__global__ __launch_bounds__(256) void k_copy(const float* __restrict__ mem,
                                              const int* __restrict__ lp,
                                              float* __restrict__ out) {
  for (int s = blockIdx.x; s < SROWS; s += gridDim.x) {
    if (lp[s] >= 0) continue;
    const f32x4* src = (const f32x4*)(mem + (size_t)s * HDIM);
    f32x4* dst = (f32x4*)(out + (size_t)s * HDIM);
    dst[threadIdx.x] = src[threadIdx.x];
  }
}

// ---------------- 256x256 8-phase fused GEMM + gates + scatter ----------------
// BM=BN=256, BK=64, 8 waves (2M x 4N), dynamic LDS 128 KiB (2 buf x (A 32K | B 32K)),
// st_16x32 swizzle, counted vmcnt(4) once per K-tile, setprio around MFMA.

#define FENCE() asm volatile("" ::: "memory")
#define BAR()   __builtin_amdgcn_s_barrier()
#define LGKM0() asm volatile("s_waitcnt lgkmcnt(0)" ::: "memory")
#define VM(N)   asm volatile("s_waitcnt vmcnt(" #N ")" ::: "memory")

#define STAGE(p0, p1, ldsoff)                                                              \
  __builtin_amdgcn_global_load_lds((const __attribute__((address_space(1))) void*)(p0),   \
      (__attribute__((address_space(3))) void*)(smem + (ldsoff) + w * 1024), 16, 0, 0);    \
  __builtin_amdgcn_global_load_lds((const __attribute__((address_space(1))) void*)(p1),   \
      (__attribute__((address_space(3))) void*)(smem + (ldsoff) + 8192 + w * 1024), 16, 0, 0);

#define LDF(base, frag, koff) (*(const short8*)(smem + (base) + (size_t)(frag) * 2048 + (koff)))

__global__ __launch_bounds__(512, 2)
void k_gru8(const unsigned short* __restrict__ Ac,
            const unsigned short* __restrict__ Bc,
            const float* __restrict__ mem,
            const int* __restrict__ sid,
            const int* __restrict__ lp,
            const float* __restrict__ btab,
            float* __restrict__ out) {
  extern __shared__ char smem[];

  const int tid  = threadIdx.x;
  const int lane = tid & 63;
  const int w    = tid >> 6;
  const int wm   = w >> 2;        // M half (0..1)
  const int wn   = w & 3;         // N quarter (0..3)
  const int l15  = lane & 15;
  const int l4   = lane >> 4;

  // XCD-aware swizzle (512 % 8 == 0 -> simple form is bijective)
  const int bid = blockIdx.x;
  const int swz = (bid & 7) * 64 + (bid >> 3);
  const int t0  = (swz >> 4) * 256;
  const int c0  = (swz & 15) * 256;

  // ---- staging source mapping (inverse st_16x32 swizzle folded in) ----
  // physical LDS byte P = R*8192 + tid*16 ; logical row = R*64 + tid>>3 ;
  // logical col(elem)  = ((tid&7)*8) ^ (((tid>>5)&1)<<4)
  const int srow0 = tid >> 3;
  const int srow1 = 64 + srow0;
  const int scol  = ((tid & 7) * 8) ^ (((tid >> 5) & 1) << 4);

  const unsigned short* pA0r0 = Ac + (size_t)(t0 +       srow0) * KDIM + scol;
  const unsigned short* pA0r1 = Ac + (size_t)(t0 +       srow1) * KDIM + scol;
  const unsigned short* pA1r0 = Ac + (size_t)(t0 + 128 + srow0) * KDIM + scol;
  const unsigned short* pA1r1 = Ac + (size_t)(t0 + 128 + srow1) * KDIM + scol;
  const unsigned short* pB0r0 = Bc + (size_t)(c0 +       srow0) * KDIM + scol;
  const unsigned short* pB0r1 = Bc + (size_t)(c0 +       srow1) * KDIM + scol;
  const unsigned short* pB1r0 = Bc + (size_t)(c0 + 128 + srow0) * KDIM + scol;
  const unsigned short* pB1r1 = Bc + (size_t)(c0 + 128 + srow1) * KDIM + scol;

  // ---- fragment read offsets (swizzled): bit = (l15>>2)&1, compile-folded ----
  const int sb    = ((l15 >> 2) & 1) << 5;
  const size_t foff0 = (size_t)l15 * 128 + ((0  + l4 * 16) ^ sb);
  const size_t foff1 = (size_t)l15 * 128 + ((64 + l4 * 16) ^ sb);

  f32x4 acc[8][4];
#pragma unroll
  for (int i = 0; i < 8; i++)
#pragma unroll
    for (int j = 0; j < 4; j++) acc[i][j] = (f32x4){0.f, 0.f, 0.f, 0.f};

  // ---- prologue: tile0 (A0,A1,B0,B1) + tile1 (B0,B1); vmcnt(4) keeps B(1) in flight
  STAGE(pA0r0, pA0r1, 0);
  STAGE(pA1r0, pA1r1, 16384);
  STAGE(pB0r0, pB0r1, 32768);
  STAGE(pB1r0, pB1r1, 49152);
  STAGE(pB0r0 + 64, pB0r1 + 64, 65536 + 32768);
  STAGE(pB1r0 + 64, pB1r1 + 64, 65536 + 49152);
  VM(4);
  FENCE(); BAR();

  for (int t = 0; t < NT; ++t) {
    const int cur = t & 1, nxt = cur ^ 1;
    const size_t abase = (size_t)cur * 65536 + (size_t)wm * 16384;
    const size_t bbase = (size_t)cur * 65536 + 32768 + (size_t)(wn >> 1) * 16384
                       + (size_t)(wn & 1) * 8192;
    const int kt1 = (t + 1 < NT) ? t + 1 : NT - 1;
    const int kt2 = (t + 2 < NT) ? t + 2 : NT - 1;

    short8 bf[4][2];
#pragma unroll
    for (int q = 0; q < 4; q++) {
      const int m0 = 2 * q;
      if (q == 0) {
#pragma unroll
        for (int n = 0; n < 4; n++) {
          bf[n][0] = LDF(bbase, n, foff0);
          bf[n][1] = LDF(bbase, n, foff1);
        }
      }
      short8 af[2][2];
      af[0][0] = LDF(abase, m0,     foff0);
      af[0][1] = LDF(abase, m0,     foff1);
      af[1][0] = LDF(abase, m0 + 1, foff0);
      af[1][1] = LDF(abase, m0 + 1, foff1);

      if (q == 0)      { STAGE(pA0r0 + kt1 * 64, pA0r1 + kt1 * 64, (size_t)nxt * 65536); }
      else if (q == 1) { STAGE(pA1r0 + kt1 * 64, pA1r1 + kt1 * 64, (size_t)nxt * 65536 + 16384); }
      else if (q == 2) { STAGE(pB0r0 + kt2 * 64, pB0r1 + kt2 * 64, (size_t)cur * 65536 + 32768); }
      else             { STAGE(pB1r0 + kt2 * 64, pB1r1 + kt2 * 64, (size_t)cur * 65536 + 49152); }

      FENCE(); BAR();
      LGKM0();
      __builtin_amdgcn_s_setprio(1);
#pragma unroll
      for (int i = 0; i < 2; i++)
#pragma unroll
        for (int n = 0; n < 4; n++) {
          acc[m0 + i][n] = __builtin_amdgcn_mfma_f32_16x16x32_bf16(af[i][0], bf[n][0], acc[m0 + i][n], 0, 0, 0);
          acc[m0 + i][n] = __builtin_amdgcn_mfma_f32_16x16x32_bf16(af[i][1], bf[n][1], acc[m0 + i][n], 0, 0, 0);
        }
      __builtin_amdgcn_s_setprio(0);
      if (q == 3) { VM(4); }
      FENCE(); BAR();
    }
  }

  // ---- epilogue: drain staging, LDS transpose per 16-row chunk, gates, scatter
  VM(0);
  __syncthreads();
  float* epi = (float*)smem;   // [8 waves][16][68]
  const int jfirst = ((c0 + wn * 64) >> 2) + l4 * 4;

#pragma unroll
  for (int mf = 0; mf < 8; mf++) {
#pragma unroll
    for (int nf = 0; nf < 4; nf++)
#pragma unroll
      for (int r = 0; r < 4; r++)
        epi[w * 1088 + (l4 * 4 + r) * 68 + nf * 16 + l15] = acc[mf][nf][r];
    __syncthreads();

    const int trow = t0 + wm * 128 + mf * 16 + l15;
    const int s    = sid[trow];
    const bool wr  = (lp[s] == trow);

    f32x4 q[4];
#pragma unroll
    for (int jj = 0; jj < 4; jj++)
      q[jj] = *(const f32x4*)&epi[w * 1088 + l15 * 68 + l4 * 16 + jj * 4];

    f32x4 hv = *(const f32x4*)&mem[(size_t)s * HDIM + jfirst];
    f32x4 o;
#pragma unroll
    for (int jj = 0; jj < 4; jj++) {
      const int j = jfirst + jj;
      f32x4 bt = *(const f32x4*)&btab[4 * j];
      float rr = fast_sigmoid(q[jj][0] + bt[0]);
      float zz = fast_sigmoid(q[jj][1] + bt[1]);
      float nn = fast_tanh(q[jj][2] + bt[2] + rr * (q[jj][3] + bt[3]));
      o[jj] = (1.0f - zz) * nn + zz * hv[jj];
    }
    if (wr) *(f32x4*)&out[(size_t)s * HDIM + jfirst] = o;
    __syncthreads();
  }
}

// ---------------- launch ----------------

extern "C" void kernel_launch(void* const* d_in, const int* in_sizes, int n_in,
                              void* d_out, int out_size, void* d_ws, size_t ws_size,
                              hipStream_t stream) {
  const float* mem = (const float*)d_in[0];
  const int*   sid = (const int*)d_in[1];
  const float* edu = (const float*)d_in[2];
  const float* Wih = (const float*)d_in[3];
  const float* Whh = (const float*)d_in[4];
  const float* bih = (const float*)d_in[5];
  const float* bhh = (const float*)d_in[6];
  float* out = (float*)d_out;

  char* p = (char*)d_ws;
  unsigned short* Ac = (unsigned short*)p; p += (size_t)TROWS * KDIM * 2;   // 32 MiB
  unsigned short* Bc = (unsigned short*)p; p += (size_t)NDIM * KDIM * 2;    // 16 MiB
  int*   lp   = (int*)p;   p += (size_t)SROWS * 4;                          // 256 KiB
  float* btab = (float*)p; p += (size_t)HDIM * 4 * 4;                       // 16 KiB

  hipFuncSetAttribute((const void*)k_gru8, hipFuncAttributeMaxDynamicSharedMemorySize, 131072);

  hipLaunchKernelGGL(k_initlp, dim3(SROWS / 256), dim3(256), 0, stream, lp);
  hipLaunchKernelGGL(k_lp, dim3(TROWS / 256), dim3(256), 0, stream, sid, lp);
  hipLaunchKernelGGL(k_bias, dim3(4), dim3(256), 0, stream, bih, bhh, btab);
  hipLaunchKernelGGL(k_build_A, dim3((TROWS * KDIM / 8) / 256), dim3(256), 0, stream, edu, mem, sid, Ac);
  hipLaunchKernelGGL(k_build_B, dim3((NDIM * KDIM / 8) / 256), dim3(256), 0, stream, Wih, Whh, Bc);
  hipLaunchKernelGGL(k_copy, dim3(8192), dim3(256), 0, stream, mem, lp, out);
  hipLaunchKernelGGL(k_gru8, dim3(512), dim3(512), 131072, stream,
                     Ac, Bc, mem, sid, lp, btab, out);
}

// Round 3
// 264.570 us; speedup vs baseline: 1.3979x; 1.0361x over previous
//
#include <hip/hip_runtime.h>
#include <hip/hip_bf16.h>
#include <stdint.h>
#include <stddef.h>

typedef short short8 __attribute__((ext_vector_type(8)));
typedef float f32x4 __attribute__((ext_vector_type(4)));

#define SROWS 65536
#define TROWS 8192
#define HDIM  1024
#define KDIM  2048   // concatenated K: [edu | h]
#define NDIM  4096   // c = 4*j + gate
#define NT    (KDIM / 64)

__device__ __forceinline__ unsigned short f2bf(float f) {
  union { float f; uint32_t u; } v; v.f = f;
  uint32_t u = v.u;
  uint32_t r = (u + 0x7FFFu + ((u >> 16) & 1u)) >> 16;
  return (unsigned short)r;
}

__device__ __forceinline__ float fast_sigmoid(float x) {
  return __builtin_amdgcn_rcpf(1.0f + __builtin_amdgcn_exp2f(-1.44269504f * x));
}
__device__ __forceinline__ float fast_tanh(float x) {
  return 1.0f - 2.0f * __builtin_amdgcn_rcpf(1.0f + __builtin_amdgcn_exp2f(2.88539008f * x));
}

// ---------------- small prep kernels ----------------

__global__ __launch_bounds__(256) void k_initlp(int* lp) {
  int i = blockIdx.x * 256 + threadIdx.x;
  if (i < SROWS) lp[i] = -1;
}

__global__ __launch_bounds__(256) void k_lp(const int* __restrict__ sid, int* lp) {
  int i = blockIdx.x * 256 + threadIdx.x;
  if (i < TROWS) atomicMax(&lp[sid[i]], i);
}

__global__ __launch_bounds__(256) void k_bias(const float* __restrict__ bih,
                                              const float* __restrict__ bhh,
                                              float* __restrict__ btab) {
  int j = blockIdx.x * 256 + threadIdx.x;
  if (j < HDIM) {
    btab[4*j+0] = bih[j] + bhh[j];
    btab[4*j+1] = bih[j+HDIM] + bhh[j+HDIM];
    btab[4*j+2] = bih[j+2*HDIM];
    btab[4*j+3] = bhh[j+2*HDIM];
  }
}

__global__ __launch_bounds__(256) void k_build_A(const float* __restrict__ edu,
                                                 const float* __restrict__ mem,
                                                 const int* __restrict__ sid,
                                                 unsigned short* __restrict__ Ac) {
  const int idx = blockIdx.x * 256 + threadIdx.x;
  const int t  = idx >> 8;
  const int k0 = (idx & 255) << 3;
  const float* src;
  if (k0 < HDIM) src = edu + (size_t)t * HDIM + k0;
  else           src = mem + (size_t)sid[t] * HDIM + (k0 - HDIM);
  f32x4 f0 = *(const f32x4*)src;
  f32x4 f1 = *(const f32x4*)(src + 4);
  short8 v;
  v[0]=(short)f2bf(f0[0]); v[1]=(short)f2bf(f0[1]); v[2]=(short)f2bf(f0[2]); v[3]=(short)f2bf(f0[3]);
  v[4]=(short)f2bf(f1[0]); v[5]=(short)f2bf(f1[1]); v[6]=(short)f2bf(f1[2]); v[7]=(short)f2bf(f1[3]);
  *(short8*)(Ac + (size_t)idx * 8) = v;
}

__global__ __launch_bounds__(256) void k_build_B(const float* __restrict__ Wih,
                                                 const float* __restrict__ Whh,
                                                 unsigned short* __restrict__ Bc) {
  const int idx = blockIdx.x * 256 + threadIdx.x;
  const int c  = idx >> 8;
  const int k0 = (idx & 255) << 3;
  const int j  = c >> 2;
  const int g  = c & 3;
  const float* src = nullptr;
  if (g == 0)      src = (k0 < HDIM) ? Wih + (size_t)j * HDIM + k0
                                     : Whh + (size_t)j * HDIM + (k0 - HDIM);
  else if (g == 1) src = (k0 < HDIM) ? Wih + (size_t)(j + HDIM) * HDIM + k0
                                     : Whh + (size_t)(j + HDIM) * HDIM + (k0 - HDIM);
  else if (g == 2) { if (k0 < HDIM)  src = Wih + (size_t)(j + 2*HDIM) * HDIM + k0; }
  else             { if (k0 >= HDIM) src = Whh + (size_t)(j + 2*HDIM) * HDIM + (k0 - HDIM); }
  short8 v = (short8)0;
  if (src) {
    f32x4 f0 = *(const f32x4*)src;
    f32x4 f1 = *(const f32x4*)(src + 4);
    v[0]=(short)f2bf(f0[0]); v[1]=(short)f2bf(f0[1]); v[2]=(short)f2bf(f0[2]); v[3]=(short)f2bf(f0[3]);
    v[4]=(short)f2bf(f1[0]); v[5]=(short)f2bf(f1[1]); v[6]=(short)f2bf(f1[2]); v[7]=(short)f2bf(f1[3]);
  }
  *(short8*)(Bc + (size_t)idx * 8) = v;
}

// ---------------- 256x256 8-phase fused GEMM + gates + scatter + copy ----------------
// BM=BN=256, BK=64, 8 waves (2M x 4N), dynamic LDS 128 KiB (2 buf x (A 32K | B 32K)),
// (row&7)<<4 XOR swizzle both sides, counted vmcnt(4) once per K-tile, setprio,
// untouched-row copy pipelined through the K-loop (load at tile t, store at t+1).

#define FENCE() asm volatile("" ::: "memory")
#define BAR()   __builtin_amdgcn_s_barrier()
#define LGKM0() asm volatile("s_waitcnt lgkmcnt(0)" ::: "memory")
#define VM(N)   asm volatile("s_waitcnt vmcnt(" #N ")" ::: "memory")

#define STAGE(p0, p1, ldsoff)                                                              \
  __builtin_amdgcn_global_load_lds((const __attribute__((address_space(1))) void*)(p0),   \
      (__attribute__((address_space(3))) void*)(smem + (ldsoff) + w * 1024), 16, 0, 0);    \
  __builtin_amdgcn_global_load_lds((const __attribute__((address_space(1))) void*)(p1),   \
      (__attribute__((address_space(3))) void*)(smem + (ldsoff) + 8192 + w * 1024), 16, 0, 0);

#define LDF(base, frag, koff) (*(const short8*)(smem + (base) + (size_t)(frag) * 2048 + (koff)))

__global__ __launch_bounds__(512, 2)
void k_gru8(const unsigned short* __restrict__ Ac,
            const unsigned short* __restrict__ Bc,
            const float* __restrict__ mem,
            const int* __restrict__ sid,
            const int* __restrict__ lp,
            const float* __restrict__ btab,
            float* __restrict__ out) {
  extern __shared__ char smem[];

  const int tid  = threadIdx.x;
  const int lane = tid & 63;
  const int w    = tid >> 6;
  const int wm   = w >> 2;        // M half (0..1)
  const int wn   = w & 3;         // N quarter (0..3)
  const int l15  = lane & 15;
  const int l4   = lane >> 4;

  // XCD-aware swizzle (512 % 8 == 0 -> bijective)
  const int bid = blockIdx.x;
  const int swz = (bid & 7) * 64 + (bid >> 3);
  const int t0  = (swz >> 4) * 256;
  const int c0  = (swz & 15) * 256;

  // ---- staging source mapping (inverse (row&7)<<4 swizzle folded in) ----
  // physical LDS: row = tid>>3 (128B rows), col_byte = (tid&7)*16
  // logical col_elem = ((tid&7)*8) ^ (((tid>>3)&7)<<3)
  const int srow0 = tid >> 3;
  const int srow1 = 64 + srow0;
  const int scol  = ((tid & 7) * 8) ^ (((tid >> 3) & 7) << 3);

  const unsigned short* pA0r0 = Ac + (size_t)(t0 +       srow0) * KDIM + scol;
  const unsigned short* pA0r1 = Ac + (size_t)(t0 +       srow1) * KDIM + scol;
  const unsigned short* pA1r0 = Ac + (size_t)(t0 + 128 + srow0) * KDIM + scol;
  const unsigned short* pA1r1 = Ac + (size_t)(t0 + 128 + srow1) * KDIM + scol;
  const unsigned short* pB0r0 = Bc + (size_t)(c0 +       srow0) * KDIM + scol;
  const unsigned short* pB0r1 = Bc + (size_t)(c0 +       srow1) * KDIM + scol;
  const unsigned short* pB1r0 = Bc + (size_t)(c0 + 128 + srow0) * KDIM + scol;
  const unsigned short* pB1r1 = Bc + (size_t)(c0 + 128 + srow1) * KDIM + scol;

  // ---- fragment read offsets: col_byte ^= (row&7)<<4 ----
  const int rsw = (l15 & 7) << 4;
  const size_t foff0 = (size_t)l15 * 128 + ((l4 * 16)      ^ rsw);
  const size_t foff1 = (size_t)l15 * 128 + ((64 + l4 * 16) ^ rsw);

  f32x4 acc[8][4];
#pragma unroll
  for (int i = 0; i < 8; i++)
#pragma unroll
    for (int j = 0; j < 4; j++) acc[i][j] = (f32x4){0.f, 0.f, 0.f, 0.f};

  // copy pipeline state (4 rows of `mem`->`out` per K-tile, untouched rows only)
  const int cbase = bid << 7;    // 128 rows per block
  f32x4 cp0, cp1;
  bool  cv0 = false, cv1 = false;
  int   cs0 = 0, cc0 = 0, cs1 = 0, cc1 = 0;

  // ---- prologue: tile0 (A0,A1,B0,B1) + tile1 (B0,B1)
  STAGE(pA0r0, pA0r1, 0);
  STAGE(pA1r0, pA1r1, 16384);
  STAGE(pB0r0, pB0r1, 32768);
  STAGE(pB1r0, pB1r1, 49152);
  STAGE(pB0r0 + 64, pB0r1 + 64, 65536 + 32768);
  STAGE(pB1r0 + 64, pB1r1 + 64, 65536 + 49152);
  VM(4);
  FENCE(); BAR();

  for (int t = 0; t < NT; ++t) {
    const int cur = t & 1, nxt = cur ^ 1;
    const size_t abase = (size_t)cur * 65536 + (size_t)wm * 16384;
    const size_t bbase = (size_t)cur * 65536 + 32768 + (size_t)(wn >> 1) * 16384
                       + (size_t)(wn & 1) * 8192;
    const int kt1 = (t + 1 < NT) ? t + 1 : NT - 1;
    const int kt2 = (t + 2 < NT) ? t + 2 : NT - 1;

    short8 bf[4][2];
#pragma unroll
    for (int q = 0; q < 4; q++) {
      const int m0 = 2 * q;
      if (q == 0) {
#pragma unroll
        for (int n = 0; n < 4; n++) {
          bf[n][0] = LDF(bbase, n, foff0);
          bf[n][1] = LDF(bbase, n, foff1);
        }
      }
      short8 af[2][2];
      af[0][0] = LDF(abase, m0,     foff0);
      af[0][1] = LDF(abase, m0,     foff1);
      af[1][0] = LDF(abase, m0 + 1, foff0);
      af[1][1] = LDF(abase, m0 + 1, foff1);

      if (q == 0)      { STAGE(pA0r0 + kt1 * 64, pA0r1 + kt1 * 64, (size_t)nxt * 65536); }
      else if (q == 1) { STAGE(pA1r0 + kt1 * 64, pA1r1 + kt1 * 64, (size_t)nxt * 65536 + 16384); }
      else if (q == 2) { STAGE(pB0r0 + kt2 * 64, pB0r1 + kt2 * 64, (size_t)cur * 65536 + 32768); }
      else             { STAGE(pB1r0 + kt2 * 64, pB1r1 + kt2 * 64, (size_t)cur * 65536 + 49152); }

      FENCE(); BAR();
      LGKM0();
      __builtin_amdgcn_s_setprio(1);
#pragma unroll
      for (int i = 0; i < 2; i++)
#pragma unroll
        for (int n = 0; n < 4; n++) {
          acc[m0 + i][n] = __builtin_amdgcn_mfma_f32_16x16x32_bf16(af[i][0], bf[n][0], acc[m0 + i][n], 0, 0, 0);
          acc[m0 + i][n] = __builtin_amdgcn_mfma_f32_16x16x32_bf16(af[i][1], bf[n][1], acc[m0 + i][n], 0, 0, 0);
        }
      __builtin_amdgcn_s_setprio(0);
      if (q == 3) {
        VM(4);
        // store previous tile's copy rows (loads completed: a full K-tile has passed)
        if (cv0) *(f32x4*)&out[(size_t)cs0 * HDIM + cc0] = cp0;
        if (cv1) *(f32x4*)&out[(size_t)cs1 * HDIM + cc1] = cp1;
        // issue this tile's copy loads (4 rows = 1024 f32x4 chunks, 2/thread)
        {
          const int i0 = t * 1024 + tid;
          cs0 = cbase + (i0 >> 8); cc0 = (i0 & 255) << 2;
          cv0 = (lp[cs0] < 0);
          if (cv0) cp0 = *(const f32x4*)&mem[(size_t)cs0 * HDIM + cc0];
          const int i1 = t * 1024 + 512 + tid;
          cs1 = cbase + (i1 >> 8); cc1 = (i1 & 255) << 2;
          cv1 = (lp[cs1] < 0);
          if (cv1) cp1 = *(const f32x4*)&mem[(size_t)cs1 * HDIM + cc1];
        }
      }
      FENCE(); BAR();
    }
  }

  // ---- drain: final copy store, then epilogue transpose + gates + scatter
  VM(0);
  if (cv0) *(f32x4*)&out[(size_t)cs0 * HDIM + cc0] = cp0;
  if (cv1) *(f32x4*)&out[(size_t)cs1 * HDIM + cc1] = cp1;
  __syncthreads();
  float* epi = (float*)smem;   // [8 waves][16][68]
  const int jfirst = ((c0 + wn * 64) >> 2) + l4 * 4;

#pragma unroll
  for (int mf = 0; mf < 8; mf++) {
#pragma unroll
    for (int nf = 0; nf < 4; nf++)
#pragma unroll
      for (int r = 0; r < 4; r++)
        epi[w * 1088 + (l4 * 4 + r) * 68 + nf * 16 + l15] = acc[mf][nf][r];
    __syncthreads();

    const int trow = t0 + wm * 128 + mf * 16 + l15;
    const int s    = sid[trow];
    const bool wr  = (lp[s] == trow);

    f32x4 q[4];
#pragma unroll
    for (int jj = 0; jj < 4; jj++)
      q[jj] = *(const f32x4*)&epi[w * 1088 + l15 * 68 + l4 * 16 + jj * 4];

    f32x4 hv = *(const f32x4*)&mem[(size_t)s * HDIM + jfirst];
    f32x4 o;
#pragma unroll
    for (int jj = 0; jj < 4; jj++) {
      const int j = jfirst + jj;
      f32x4 bt = *(const f32x4*)&btab[4 * j];
      float rr = fast_sigmoid(q[jj][0] + bt[0]);
      float zz = fast_sigmoid(q[jj][1] + bt[1]);
      float nn = fast_tanh(q[jj][2] + bt[2] + rr * (q[jj][3] + bt[3]));
      o[jj] = (1.0f - zz) * nn + zz * hv[jj];
    }
    if (wr) *(f32x4*)&out[(size_t)s * HDIM + jfirst] = o;
    __syncthreads();
  }
}

// ---------------- launch ----------------

extern "C" void kernel_launch(void* const* d_in, const int* in_sizes, int n_in,
                              void* d_out, int out_size, void* d_ws, size_t ws_size,
                              hipStream_t stream) {
  const float* mem = (const float*)d_in[0];
  const int*   sid = (const int*)d_in[1];
  const float* edu = (const float*)d_in[2];
  const float* Wih = (const float*)d_in[3];
  const float* Whh = (const float*)d_in[4];
  const float* bih = (const float*)d_in[5];
  const float* bhh = (const float*)d_in[6];
  float* out = (float*)d_out;

  char* p = (char*)d_ws;
  unsigned short* Ac = (unsigned short*)p; p += (size_t)TROWS * KDIM * 2;   // 32 MiB
  unsigned short* Bc = (unsigned short*)p; p += (size_t)NDIM * KDIM * 2;    // 16 MiB
  int*   lp   = (int*)p;   p += (size_t)SROWS * 4;                          // 256 KiB
  float* btab = (float*)p; p += (size_t)HDIM * 4 * 4;                       // 16 KiB

  hipFuncSetAttribute((const void*)k_gru8, hipFuncAttributeMaxDynamicSharedMemorySize, 131072);

  hipLaunchKernelGGL(k_initlp, dim3(SROWS / 256), dim3(256), 0, stream, lp);
  hipLaunchKernelGGL(k_lp, dim3(TROWS / 256), dim3(256), 0, stream, sid, lp);
  hipLaunchKernelGGL(k_bias, dim3(4), dim3(256), 0, stream, bih, bhh, btab);
  hipLaunchKernelGGL(k_build_A, dim3((TROWS * KDIM / 8) / 256), dim3(256), 0, stream, edu, mem, sid, Ac);
  hipLaunchKernelGGL(k_build_B, dim3((NDIM * KDIM / 8) / 256), dim3(256), 0, stream, Wih, Whh, Bc);
  hipLaunchKernelGGL(k_gru8, dim3(512), dim3(512), 131072, stream,
                     Ac, Bc, mem, sid, lp, btab, out);
}

// Round 4
// 257.957 us; speedup vs baseline: 1.4337x; 1.0256x over previous
//
#include <hip/hip_runtime.h>
#include <hip/hip_bf16.h>
#include <stdint.h>
#include <stddef.h>

typedef short short8 __attribute__((ext_vector_type(8)));
typedef float f32x4 __attribute__((ext_vector_type(4)));

#define SROWS 65536
#define TROWS 8192
#define HDIM  1024
#define KDIM  2048   // concatenated K: [edu | h]
#define NDIM  4096   // c = 4*j + gate
#define NT    (KDIM / 64)

__device__ __forceinline__ unsigned short f2bf(float f) {
  union { float f; uint32_t u; } v; v.f = f;
  uint32_t u = v.u;
  uint32_t r = (u + 0x7FFFu + ((u >> 16) & 1u)) >> 16;
  return (unsigned short)r;
}

__device__ __forceinline__ float fast_sigmoid(float x) {
  return __builtin_amdgcn_rcpf(1.0f + __builtin_amdgcn_exp2f(-1.44269504f * x));
}
__device__ __forceinline__ float fast_tanh(float x) {
  return 1.0f - 2.0f * __builtin_amdgcn_rcpf(1.0f + __builtin_amdgcn_exp2f(2.88539008f * x));
}

// ---------------- small prep kernels ----------------

__global__ __launch_bounds__(256) void k_initlp(int* lp) {
  int i = blockIdx.x * 256 + threadIdx.x;
  if (i < SROWS) lp[i] = -1;
}

__global__ __launch_bounds__(256) void k_lp(const int* __restrict__ sid, int* lp) {
  int i = blockIdx.x * 256 + threadIdx.x;
  if (i < TROWS) atomicMax(&lp[sid[i]], i);
}

// per-row "untouched" bitmask: bit r of flagb[r>>6] = (lp[r] < 0)
__global__ __launch_bounds__(256) void k_flags(const int* __restrict__ lp,
                                               unsigned long long* __restrict__ flagb) {
  int i = blockIdx.x * 256 + threadIdx.x;
  unsigned long long m = __ballot(lp[i] < 0);
  if ((threadIdx.x & 63) == 0) flagb[i >> 6] = m;
}

__global__ __launch_bounds__(256) void k_bias(const float* __restrict__ bih,
                                              const float* __restrict__ bhh,
                                              float* __restrict__ btab) {
  int j = blockIdx.x * 256 + threadIdx.x;
  if (j < HDIM) {
    btab[4*j+0] = bih[j] + bhh[j];
    btab[4*j+1] = bih[j+HDIM] + bhh[j+HDIM];
    btab[4*j+2] = bih[j+2*HDIM];
    btab[4*j+3] = bhh[j+2*HDIM];
  }
}

__global__ __launch_bounds__(256) void k_build_A(const float* __restrict__ edu,
                                                 const float* __restrict__ mem,
                                                 const int* __restrict__ sid,
                                                 unsigned short* __restrict__ Ac) {
  const int idx = blockIdx.x * 256 + threadIdx.x;
  const int t  = idx >> 8;
  const int k0 = (idx & 255) << 3;
  const float* src;
  if (k0 < HDIM) src = edu + (size_t)t * HDIM + k0;
  else           src = mem + (size_t)sid[t] * HDIM + (k0 - HDIM);
  f32x4 f0 = *(const f32x4*)src;
  f32x4 f1 = *(const f32x4*)(src + 4);
  short8 v;
  v[0]=(short)f2bf(f0[0]); v[1]=(short)f2bf(f0[1]); v[2]=(short)f2bf(f0[2]); v[3]=(short)f2bf(f0[3]);
  v[4]=(short)f2bf(f1[0]); v[5]=(short)f2bf(f1[1]); v[6]=(short)f2bf(f1[2]); v[7]=(short)f2bf(f1[3]);
  *(short8*)(Ac + (size_t)idx * 8) = v;
}

__global__ __launch_bounds__(256) void k_build_B(const float* __restrict__ Wih,
                                                 const float* __restrict__ Whh,
                                                 unsigned short* __restrict__ Bc) {
  const int idx = blockIdx.x * 256 + threadIdx.x;
  const int c  = idx >> 8;
  const int k0 = (idx & 255) << 3;
  const int j  = c >> 2;
  const int g  = c & 3;
  const float* src = nullptr;
  if (g == 0)      src = (k0 < HDIM) ? Wih + (size_t)j * HDIM + k0
                                     : Whh + (size_t)j * HDIM + (k0 - HDIM);
  else if (g == 1) src = (k0 < HDIM) ? Wih + (size_t)(j + HDIM) * HDIM + k0
                                     : Whh + (size_t)(j + HDIM) * HDIM + (k0 - HDIM);
  else if (g == 2) { if (k0 < HDIM)  src = Wih + (size_t)(j + 2*HDIM) * HDIM + k0; }
  else             { if (k0 >= HDIM) src = Whh + (size_t)(j + 2*HDIM) * HDIM + (k0 - HDIM); }
  short8 v = (short8)0;
  if (src) {
    f32x4 f0 = *(const f32x4*)src;
    f32x4 f1 = *(const f32x4*)(src + 4);
    v[0]=(short)f2bf(f0[0]); v[1]=(short)f2bf(f0[1]); v[2]=(short)f2bf(f0[2]); v[3]=(short)f2bf(f0[3]);
    v[4]=(short)f2bf(f1[0]); v[5]=(short)f2bf(f1[1]); v[6]=(short)f2bf(f1[2]); v[7]=(short)f2bf(f1[3]);
  }
  *(short8*)(Bc + (size_t)idx * 8) = v;
}

// ---------------- 256x256 8-phase fused GEMM + gates + scatter + copy ----------------
// BM=BN=256, BK=64, 8 waves (2M x 4N), dynamic LDS 128 KiB (2 buf x (A 32K | B 32K)),
// (row&7)<<4 XOR swizzle both sides, counted vmcnt(4) once per K-tile, setprio.
// Untouched-row copy pipelined through the K-loop; copy predicate from a
// preloaded SGPR bitmask (NO in-loop dependent loads -> no vmcnt drain).

#define FENCE() asm volatile("" ::: "memory")
#define BAR()   __builtin_amdgcn_s_barrier()
#define LGKM0() asm volatile("s_waitcnt lgkmcnt(0)" ::: "memory")
#define VM(N)   asm volatile("s_waitcnt vmcnt(" #N ")" ::: "memory")

#define STAGE(p0, p1, ldsoff)                                                              \
  __builtin_amdgcn_global_load_lds((const __attribute__((address_space(1))) void*)(p0),   \
      (__attribute__((address_space(3))) void*)(smem + (ldsoff) + w * 1024), 16, 0, 0);    \
  __builtin_amdgcn_global_load_lds((const __attribute__((address_space(1))) void*)(p1),   \
      (__attribute__((address_space(3))) void*)(smem + (ldsoff) + 8192 + w * 1024), 16, 0, 0);

#define LDF(base, frag, koff) (*(const short8*)(smem + (base) + (size_t)(frag) * 2048 + (koff)))

__global__ __launch_bounds__(512, 2)
void k_gru8(const unsigned short* __restrict__ Ac,
            const unsigned short* __restrict__ Bc,
            const float* __restrict__ mem,
            const int* __restrict__ sid,
            const int* __restrict__ lp,
            const unsigned long long* __restrict__ flagb,
            const float* __restrict__ btab,
            float* __restrict__ out) {
  extern __shared__ char smem[];

  const int tid  = threadIdx.x;
  const int lane = tid & 63;
  const int w    = tid >> 6;
  const int wm   = w >> 2;        // M half (0..1)
  const int wn   = w & 3;         // N quarter (0..3)
  const int l15  = lane & 15;
  const int l4   = lane >> 4;

  // XCD-aware swizzle (512 % 8 == 0 -> bijective)
  const int bid = blockIdx.x;
  const int swz = (bid & 7) * 64 + (bid >> 3);
  const int t0  = (swz >> 4) * 256;
  const int c0  = (swz & 15) * 256;

  // ---- staging source mapping (inverse (row&7)<<4 swizzle folded in) ----
  const int srow0 = tid >> 3;
  const int srow1 = 64 + srow0;
  const int scol  = ((tid & 7) * 8) ^ (((tid >> 3) & 7) << 3);

  const unsigned short* pA0r0 = Ac + (size_t)(t0 +       srow0) * KDIM + scol;
  const unsigned short* pA0r1 = Ac + (size_t)(t0 +       srow1) * KDIM + scol;
  const unsigned short* pA1r0 = Ac + (size_t)(t0 + 128 + srow0) * KDIM + scol;
  const unsigned short* pA1r1 = Ac + (size_t)(t0 + 128 + srow1) * KDIM + scol;
  const unsigned short* pB0r0 = Bc + (size_t)(c0 +       srow0) * KDIM + scol;
  const unsigned short* pB0r1 = Bc + (size_t)(c0 +       srow1) * KDIM + scol;
  const unsigned short* pB1r0 = Bc + (size_t)(c0 + 128 + srow0) * KDIM + scol;
  const unsigned short* pB1r1 = Bc + (size_t)(c0 + 128 + srow1) * KDIM + scol;

  // ---- fragment read offsets: col_byte ^= (row&7)<<4 ----
  const int rsw = (l15 & 7) << 4;
  const size_t foff0 = (size_t)l15 * 128 + ((l4 * 16)      ^ rsw);
  const size_t foff1 = (size_t)l15 * 128 + ((64 + l4 * 16) ^ rsw);

  f32x4 acc[8][4];
#pragma unroll
  for (int i = 0; i < 8; i++)
#pragma unroll
    for (int j = 0; j < 4; j++) acc[i][j] = (f32x4){0.f, 0.f, 0.f, 0.f};

  // copy pipeline state (4 rows of `mem`->`out` per K-tile, untouched rows only)
  const int cbase = bid << 7;                       // 128 rows per block
  const unsigned long long fw0 = flagb[bid * 2];    // rows [cbase, cbase+64)
  const unsigned long long fw1 = flagb[bid * 2 + 1];// rows [cbase+64, cbase+128)
  const int ccp  = tid >> 8;                        // 0 or 1
  const int ccol = (tid & 255) << 2;                // column (f32 elems)
  f32x4 cp0, cp1;
  bool  cv0 = false, cv1 = false;
  int   cs0 = 0, cs1 = 0;

  // ---- prologue: tile0 (A0,A1,B0,B1) + tile1 (B0,B1)
  STAGE(pA0r0, pA0r1, 0);
  STAGE(pA1r0, pA1r1, 16384);
  STAGE(pB0r0, pB0r1, 32768);
  STAGE(pB1r0, pB1r1, 49152);
  STAGE(pB0r0 + 64, pB0r1 + 64, 65536 + 32768);
  STAGE(pB1r0 + 64, pB1r1 + 64, 65536 + 49152);
  VM(4);
  FENCE(); BAR();

  for (int t = 0; t < NT; ++t) {
    const int cur = t & 1, nxt = cur ^ 1;
    const size_t abase = (size_t)cur * 65536 + (size_t)wm * 16384;
    const size_t bbase = (size_t)cur * 65536 + 32768 + (size_t)(wn >> 1) * 16384
                       + (size_t)(wn & 1) * 8192;
    const int kt1 = (t + 1 < NT) ? t + 1 : NT - 1;
    const int kt2 = (t + 2 < NT) ? t + 2 : NT - 1;

    short8 bf[4][2];
#pragma unroll
    for (int q = 0; q < 4; q++) {
      const int m0 = 2 * q;
      if (q == 0) {
#pragma unroll
        for (int n = 0; n < 4; n++) {
          bf[n][0] = LDF(bbase, n, foff0);
          bf[n][1] = LDF(bbase, n, foff1);
        }
      }
      short8 af[2][2];
      af[0][0] = LDF(abase, m0,     foff0);
      af[0][1] = LDF(abase, m0,     foff1);
      af[1][0] = LDF(abase, m0 + 1, foff0);
      af[1][1] = LDF(abase, m0 + 1, foff1);

      if (q == 0)      { STAGE(pA0r0 + kt1 * 64, pA0r1 + kt1 * 64, (size_t)nxt * 65536); }
      else if (q == 1) { STAGE(pA1r0 + kt1 * 64, pA1r1 + kt1 * 64, (size_t)nxt * 65536 + 16384); }
      else if (q == 2) { STAGE(pB0r0 + kt2 * 64, pB0r1 + kt2 * 64, (size_t)cur * 65536 + 32768); }
      else             { STAGE(pB1r0 + kt2 * 64, pB1r1 + kt2 * 64, (size_t)cur * 65536 + 49152); }

      FENCE(); BAR();
      LGKM0();
      __builtin_amdgcn_s_setprio(1);
#pragma unroll
      for (int i = 0; i < 2; i++)
#pragma unroll
        for (int n = 0; n < 4; n++) {
          acc[m0 + i][n] = __builtin_amdgcn_mfma_f32_16x16x32_bf16(af[i][0], bf[n][0], acc[m0 + i][n], 0, 0, 0);
          acc[m0 + i][n] = __builtin_amdgcn_mfma_f32_16x16x32_bf16(af[i][1], bf[n][1], acc[m0 + i][n], 0, 0, 0);
        }
      __builtin_amdgcn_s_setprio(0);
      if (q == 3) {
        VM(4);
        // store previous tile's copy rows (VM(4) + 8 newer stage ops => loads retired)
        if (cv0) *(f32x4*)&out[(size_t)cs0 * HDIM + ccol] = cp0;
        if (cv1) *(f32x4*)&out[(size_t)cs1 * HDIM + ccol] = cp1;
        // issue this tile's copy loads; predicate from SGPR bitmask (no VMEM dep)
        {
          const int rr0 = 4 * t + ccp, rr1 = rr0 + 2;
          const unsigned long long fwt = (t < 16) ? fw0 : fw1;
          cv0 = (fwt >> (rr0 & 63)) & 1ull;
          cv1 = (fwt >> (rr1 & 63)) & 1ull;
          cs0 = cbase + rr0; cs1 = cbase + rr1;
          if (cv0) cp0 = *(const f32x4*)&mem[(size_t)cs0 * HDIM + ccol];
          if (cv1) cp1 = *(const f32x4*)&mem[(size_t)cs1 * HDIM + ccol];
        }
      }
      FENCE(); BAR();
    }
  }

  // ---- drain: final copy store, then epilogue transpose + gates + scatter
  VM(0);
  if (cv0) *(f32x4*)&out[(size_t)cs0 * HDIM + ccol] = cp0;
  if (cv1) *(f32x4*)&out[(size_t)cs1 * HDIM + ccol] = cp1;
  __syncthreads();
  float* epi = (float*)smem;   // [8 waves][16][68]
  const int jfirst = ((c0 + wn * 64) >> 2) + l4 * 4;

#pragma unroll
  for (int mf = 0; mf < 8; mf++) {
#pragma unroll
    for (int nf = 0; nf < 4; nf++)
#pragma unroll
      for (int r = 0; r < 4; r++)
        epi[w * 1088 + (l4 * 4 + r) * 68 + nf * 16 + l15] = acc[mf][nf][r];
    __syncthreads();

    const int trow = t0 + wm * 128 + mf * 16 + l15;
    const int s    = sid[trow];
    const bool wr  = (lp[s] == trow);

    f32x4 q[4];
#pragma unroll
    for (int jj = 0; jj < 4; jj++)
      q[jj] = *(const f32x4*)&epi[w * 1088 + l15 * 68 + l4 * 16 + jj * 4];

    f32x4 hv = *(const f32x4*)&mem[(size_t)s * HDIM + jfirst];
    f32x4 o;
#pragma unroll
    for (int jj = 0; jj < 4; jj++) {
      const int j = jfirst + jj;
      f32x4 bt = *(const f32x4*)&btab[4 * j];
      float rr = fast_sigmoid(q[jj][0] + bt[0]);
      float zz = fast_sigmoid(q[jj][1] + bt[1]);
      float nn = fast_tanh(q[jj][2] + bt[2] + rr * (q[jj][3] + bt[3]));
      o[jj] = (1.0f - zz) * nn + zz * hv[jj];
    }
    if (wr) *(f32x4*)&out[(size_t)s * HDIM + jfirst] = o;
    __syncthreads();
  }
}

// ---------------- launch ----------------

extern "C" void kernel_launch(void* const* d_in, const int* in_sizes, int n_in,
                              void* d_out, int out_size, void* d_ws, size_t ws_size,
                              hipStream_t stream) {
  const float* mem = (const float*)d_in[0];
  const int*   sid = (const int*)d_in[1];
  const float* edu = (const float*)d_in[2];
  const float* Wih = (const float*)d_in[3];
  const float* Whh = (const float*)d_in[4];
  const float* bih = (const float*)d_in[5];
  const float* bhh = (const float*)d_in[6];
  float* out = (float*)d_out;

  char* p = (char*)d_ws;
  unsigned short* Ac = (unsigned short*)p; p += (size_t)TROWS * KDIM * 2;   // 32 MiB
  unsigned short* Bc = (unsigned short*)p; p += (size_t)NDIM * KDIM * 2;    // 16 MiB
  int*   lp   = (int*)p;   p += (size_t)SROWS * 4;                          // 256 KiB
  float* btab = (float*)p; p += (size_t)HDIM * 4 * 4;                       // 16 KiB
  unsigned long long* flagb = (unsigned long long*)p; p += (size_t)(SROWS / 64) * 8; // 8 KiB

  hipFuncSetAttribute((const void*)k_gru8, hipFuncAttributeMaxDynamicSharedMemorySize, 131072);

  hipLaunchKernelGGL(k_initlp, dim3(SROWS / 256), dim3(256), 0, stream, lp);
  hipLaunchKernelGGL(k_lp, dim3(TROWS / 256), dim3(256), 0, stream, sid, lp);
  hipLaunchKernelGGL(k_flags, dim3(SROWS / 256), dim3(256), 0, stream, lp, flagb);
  hipLaunchKernelGGL(k_bias, dim3(4), dim3(256), 0, stream, bih, bhh, btab);
  hipLaunchKernelGGL(k_build_A, dim3((TROWS * KDIM / 8) / 256), dim3(256), 0, stream, edu, mem, sid, Ac);
  hipLaunchKernelGGL(k_build_B, dim3((NDIM * KDIM / 8) / 256), dim3(256), 0, stream, Wih, Whh, Bc);
  hipLaunchKernelGGL(k_gru8, dim3(512), dim3(512), 131072, stream,
                     Ac, Bc, mem, sid, lp, flagb, btab, out);
}

// Round 5
// 246.891 us; speedup vs baseline: 1.4980x; 1.0448x over previous
//
#include <hip/hip_runtime.h>
#include <hip/hip_bf16.h>
#include <stdint.h>
#include <stddef.h>

typedef short short8 __attribute__((ext_vector_type(8)));
typedef float f32x4 __attribute__((ext_vector_type(4)));

#define SROWS 65536
#define TROWS 8192
#define HDIM  1024
#define KDIM  2048   // concatenated K: [edu | h]
#define NDIM  4096   // c = 4*j + gate
#define NT    (KDIM / 64)

__device__ __forceinline__ unsigned short f2bf(float f) {
  union { float f; uint32_t u; } v; v.f = f;
  uint32_t u = v.u;
  uint32_t r = (u + 0x7FFFu + ((u >> 16) & 1u)) >> 16;
  return (unsigned short)r;
}

__device__ __forceinline__ float fast_sigmoid(float x) {
  return __builtin_amdgcn_rcpf(1.0f + __builtin_amdgcn_exp2f(-1.44269504f * x));
}
__device__ __forceinline__ float fast_tanh(float x) {
  return 1.0f - 2.0f * __builtin_amdgcn_rcpf(1.0f + __builtin_amdgcn_exp2f(2.88539008f * x));
}

// ---------------- small prep kernels ----------------

__global__ __launch_bounds__(256) void k_initlp(int* lp) {
  int i = blockIdx.x * 256 + threadIdx.x;
  if (i < SROWS) lp[i] = -1;
}

__global__ __launch_bounds__(256) void k_lp(const int* __restrict__ sid, int* lp) {
  int i = blockIdx.x * 256 + threadIdx.x;
  if (i < TROWS) atomicMax(&lp[sid[i]], i);
}

// per-row "untouched" bitmask: bit r of flagb[r>>6] = (lp[r] < 0)
__global__ __launch_bounds__(256) void k_flags(const int* __restrict__ lp,
                                               unsigned long long* __restrict__ flagb) {
  int i = blockIdx.x * 256 + threadIdx.x;
  unsigned long long m = __ballot(lp[i] < 0);
  if ((threadIdx.x & 63) == 0) flagb[i >> 6] = m;
}

__global__ __launch_bounds__(256) void k_bias(const float* __restrict__ bih,
                                              const float* __restrict__ bhh,
                                              float* __restrict__ btab) {
  int j = blockIdx.x * 256 + threadIdx.x;
  if (j < HDIM) {
    btab[4*j+0] = bih[j] + bhh[j];
    btab[4*j+1] = bih[j+HDIM] + bhh[j+HDIM];
    btab[4*j+2] = bih[j+2*HDIM];
    btab[4*j+3] = bhh[j+2*HDIM];
  }
}

__global__ __launch_bounds__(256) void k_build_A(const float* __restrict__ edu,
                                                 const float* __restrict__ mem,
                                                 const int* __restrict__ sid,
                                                 unsigned short* __restrict__ Ac) {
  const int idx = blockIdx.x * 256 + threadIdx.x;
  const int t  = idx >> 8;
  const int k0 = (idx & 255) << 3;
  const float* src;
  if (k0 < HDIM) src = edu + (size_t)t * HDIM + k0;
  else           src = mem + (size_t)sid[t] * HDIM + (k0 - HDIM);
  f32x4 f0 = *(const f32x4*)src;
  f32x4 f1 = *(const f32x4*)(src + 4);
  short8 v;
  v[0]=(short)f2bf(f0[0]); v[1]=(short)f2bf(f0[1]); v[2]=(short)f2bf(f0[2]); v[3]=(short)f2bf(f0[3]);
  v[4]=(short)f2bf(f1[0]); v[5]=(short)f2bf(f1[1]); v[6]=(short)f2bf(f1[2]); v[7]=(short)f2bf(f1[3]);
  *(short8*)(Ac + (size_t)idx * 8) = v;
}

__global__ __launch_bounds__(256) void k_build_B(const float* __restrict__ Wih,
                                                 const float* __restrict__ Whh,
                                                 unsigned short* __restrict__ Bc) {
  const int idx = blockIdx.x * 256 + threadIdx.x;
  const int c  = idx >> 8;
  const int k0 = (idx & 255) << 3;
  const int j  = c >> 2;
  const int g  = c & 3;
  const float* src = nullptr;
  if (g == 0)      src = (k0 < HDIM) ? Wih + (size_t)j * HDIM + k0
                                     : Whh + (size_t)j * HDIM + (k0 - HDIM);
  else if (g == 1) src = (k0 < HDIM) ? Wih + (size_t)(j + HDIM) * HDIM + k0
                                     : Whh + (size_t)(j + HDIM) * HDIM + (k0 - HDIM);
  else if (g == 2) { if (k0 < HDIM)  src = Wih + (size_t)(j + 2*HDIM) * HDIM + k0; }
  else             { if (k0 >= HDIM) src = Whh + (size_t)(j + 2*HDIM) * HDIM + (k0 - HDIM); }
  short8 v = (short8)0;
  if (src) {
    f32x4 f0 = *(const f32x4*)src;
    f32x4 f1 = *(const f32x4*)(src + 4);
    v[0]=(short)f2bf(f0[0]); v[1]=(short)f2bf(f0[1]); v[2]=(short)f2bf(f0[2]); v[3]=(short)f2bf(f0[3]);
    v[4]=(short)f2bf(f1[0]); v[5]=(short)f2bf(f1[1]); v[6]=(short)f2bf(f1[2]); v[7]=(short)f2bf(f1[3]);
  }
  *(short8*)(Bc + (size_t)idx * 8) = v;
}

// ---------------- 256x256 8-phase fused GEMM + gates + scatter + copy ----------------
// BM=BN=256, BK=64, 8 waves (2M x 4N), dynamic LDS 128 KiB (2 buf x (A 32K | B 32K)),
// (row&7)<<4 XOR swizzle both sides, counted vmcnt(4) once per K-tile, setprio.
// Untouched-row copy pipelined through the K-loop with NON-TEMPORAL ld/st so the
// 460 MB copy stream does not evict the L2-resident Ac/Bc staging tiles.

#define FENCE() asm volatile("" ::: "memory")
#define BAR()   __builtin_amdgcn_s_barrier()
#define LGKM0() asm volatile("s_waitcnt lgkmcnt(0)" ::: "memory")
#define VM(N)   asm volatile("s_waitcnt vmcnt(" #N ")" ::: "memory")

#define STAGE(p0, p1, ldsoff)                                                              \
  __builtin_amdgcn_global_load_lds((const __attribute__((address_space(1))) void*)(p0),   \
      (__attribute__((address_space(3))) void*)(smem + (ldsoff) + w * 1024), 16, 0, 0);    \
  __builtin_amdgcn_global_load_lds((const __attribute__((address_space(1))) void*)(p1),   \
      (__attribute__((address_space(3))) void*)(smem + (ldsoff) + 8192 + w * 1024), 16, 0, 0);

#define LDF(base, frag, koff) (*(const short8*)(smem + (base) + (size_t)(frag) * 2048 + (koff)))

__global__ __launch_bounds__(512, 2)
void k_gru8(const unsigned short* __restrict__ Ac,
            const unsigned short* __restrict__ Bc,
            const float* __restrict__ mem,
            const int* __restrict__ sid,
            const int* __restrict__ lp,
            const unsigned long long* __restrict__ flagb,
            const float* __restrict__ btab,
            float* __restrict__ out) {
  extern __shared__ char smem[];

  const int tid  = threadIdx.x;
  const int lane = tid & 63;
  const int w    = tid >> 6;
  const int wm   = w >> 2;        // M half (0..1)
  const int wn   = w & 3;         // N quarter (0..3)
  const int l15  = lane & 15;
  const int l4   = lane >> 4;

  // XCD-aware swizzle (512 % 8 == 0 -> bijective)
  const int bid = blockIdx.x;
  const int swz = (bid & 7) * 64 + (bid >> 3);
  const int t0  = (swz >> 4) * 256;
  const int c0  = (swz & 15) * 256;

  // ---- staging source mapping (inverse (row&7)<<4 swizzle folded in) ----
  const int srow0 = tid >> 3;
  const int srow1 = 64 + srow0;
  const int scol  = ((tid & 7) * 8) ^ (((tid >> 3) & 7) << 3);

  const unsigned short* pA0r0 = Ac + (size_t)(t0 +       srow0) * KDIM + scol;
  const unsigned short* pA0r1 = Ac + (size_t)(t0 +       srow1) * KDIM + scol;
  const unsigned short* pA1r0 = Ac + (size_t)(t0 + 128 + srow0) * KDIM + scol;
  const unsigned short* pA1r1 = Ac + (size_t)(t0 + 128 + srow1) * KDIM + scol;
  const unsigned short* pB0r0 = Bc + (size_t)(c0 +       srow0) * KDIM + scol;
  const unsigned short* pB0r1 = Bc + (size_t)(c0 +       srow1) * KDIM + scol;
  const unsigned short* pB1r0 = Bc + (size_t)(c0 + 128 + srow0) * KDIM + scol;
  const unsigned short* pB1r1 = Bc + (size_t)(c0 + 128 + srow1) * KDIM + scol;

  // ---- fragment read offsets: col_byte ^= (row&7)<<4 ----
  const int rsw = (l15 & 7) << 4;
  const size_t foff0 = (size_t)l15 * 128 + ((l4 * 16)      ^ rsw);
  const size_t foff1 = (size_t)l15 * 128 + ((64 + l4 * 16) ^ rsw);

  f32x4 acc[8][4];
#pragma unroll
  for (int i = 0; i < 8; i++)
#pragma unroll
    for (int j = 0; j < 4; j++) acc[i][j] = (f32x4){0.f, 0.f, 0.f, 0.f};

  // copy pipeline state (4 rows of `mem`->`out` per K-tile, untouched rows only)
  const int cbase = bid << 7;                       // 128 rows per block
  const unsigned long long fw0 = flagb[bid * 2];    // rows [cbase, cbase+64)
  const unsigned long long fw1 = flagb[bid * 2 + 1];// rows [cbase+64, cbase+128)
  const int ccp  = tid >> 8;                        // 0 or 1
  const int ccol = (tid & 255) << 2;                // column (f32 elems)
  f32x4 cp0, cp1;
  bool  cv0 = false, cv1 = false;
  int   cs0 = 0, cs1 = 0;

  // ---- prologue: tile0 (A0,A1,B0,B1) + tile1 (B0,B1)
  STAGE(pA0r0, pA0r1, 0);
  STAGE(pA1r0, pA1r1, 16384);
  STAGE(pB0r0, pB0r1, 32768);
  STAGE(pB1r0, pB1r1, 49152);
  STAGE(pB0r0 + 64, pB0r1 + 64, 65536 + 32768);
  STAGE(pB1r0 + 64, pB1r1 + 64, 65536 + 49152);
  VM(4);
  FENCE(); BAR();

  for (int t = 0; t < NT; ++t) {
    const int cur = t & 1, nxt = cur ^ 1;
    const size_t abase = (size_t)cur * 65536 + (size_t)wm * 16384;
    const size_t bbase = (size_t)cur * 65536 + 32768 + (size_t)(wn >> 1) * 16384
                       + (size_t)(wn & 1) * 8192;
    const int kt1 = (t + 1 < NT) ? t + 1 : NT - 1;
    const int kt2 = (t + 2 < NT) ? t + 2 : NT - 1;

    short8 bf[4][2];
#pragma unroll
    for (int q = 0; q < 4; q++) {
      const int m0 = 2 * q;
      if (q == 0) {
#pragma unroll
        for (int n = 0; n < 4; n++) {
          bf[n][0] = LDF(bbase, n, foff0);
          bf[n][1] = LDF(bbase, n, foff1);
        }
      }
      short8 af[2][2];
      af[0][0] = LDF(abase, m0,     foff0);
      af[0][1] = LDF(abase, m0,     foff1);
      af[1][0] = LDF(abase, m0 + 1, foff0);
      af[1][1] = LDF(abase, m0 + 1, foff1);

      if (q == 0)      { STAGE(pA0r0 + kt1 * 64, pA0r1 + kt1 * 64, (size_t)nxt * 65536); }
      else if (q == 1) { STAGE(pA1r0 + kt1 * 64, pA1r1 + kt1 * 64, (size_t)nxt * 65536 + 16384); }
      else if (q == 2) { STAGE(pB0r0 + kt2 * 64, pB0r1 + kt2 * 64, (size_t)cur * 65536 + 32768); }
      else             { STAGE(pB1r0 + kt2 * 64, pB1r1 + kt2 * 64, (size_t)cur * 65536 + 49152); }

      FENCE(); BAR();
      LGKM0();
      __builtin_amdgcn_s_setprio(1);
#pragma unroll
      for (int i = 0; i < 2; i++)
#pragma unroll
        for (int n = 0; n < 4; n++) {
          acc[m0 + i][n] = __builtin_amdgcn_mfma_f32_16x16x32_bf16(af[i][0], bf[n][0], acc[m0 + i][n], 0, 0, 0);
          acc[m0 + i][n] = __builtin_amdgcn_mfma_f32_16x16x32_bf16(af[i][1], bf[n][1], acc[m0 + i][n], 0, 0, 0);
        }
      __builtin_amdgcn_s_setprio(0);
      if (q == 3) {
        VM(4);
        // store previous tile's copy rows (non-temporal: bypass L2)
        if (cv0) __builtin_nontemporal_store(cp0, (f32x4*)&out[(size_t)cs0 * HDIM + ccol]);
        if (cv1) __builtin_nontemporal_store(cp1, (f32x4*)&out[(size_t)cs1 * HDIM + ccol]);
        // issue this tile's copy loads (non-temporal); predicate from SGPR bitmask
        {
          const int rr0 = 4 * t + ccp, rr1 = rr0 + 2;
          const unsigned long long fwt = (t < 16) ? fw0 : fw1;
          cv0 = (fwt >> (rr0 & 63)) & 1ull;
          cv1 = (fwt >> (rr1 & 63)) & 1ull;
          cs0 = cbase + rr0; cs1 = cbase + rr1;
          if (cv0) cp0 = __builtin_nontemporal_load((const f32x4*)&mem[(size_t)cs0 * HDIM + ccol]);
          if (cv1) cp1 = __builtin_nontemporal_load((const f32x4*)&mem[(size_t)cs1 * HDIM + ccol]);
        }
      }
      FENCE(); BAR();
    }
  }

  // ---- drain: final copy store, then epilogue transpose + gates + scatter
  VM(0);
  if (cv0) __builtin_nontemporal_store(cp0, (f32x4*)&out[(size_t)cs0 * HDIM + ccol]);
  if (cv1) __builtin_nontemporal_store(cp1, (f32x4*)&out[(size_t)cs1 * HDIM + ccol]);
  __syncthreads();
  float* epi = (float*)smem;   // [8 waves][16][68]
  const int jfirst = ((c0 + wn * 64) >> 2) + l4 * 4;

#pragma unroll
  for (int mf = 0; mf < 8; mf++) {
#pragma unroll
    for (int nf = 0; nf < 4; nf++)
#pragma unroll
      for (int r = 0; r < 4; r++)
        epi[w * 1088 + (l4 * 4 + r) * 68 + nf * 16 + l15] = acc[mf][nf][r];
    __syncthreads();

    const int trow = t0 + wm * 128 + mf * 16 + l15;
    const int s    = sid[trow];
    const bool wr  = (lp[s] == trow);

    f32x4 q[4];
#pragma unroll
    for (int jj = 0; jj < 4; jj++)
      q[jj] = *(const f32x4*)&epi[w * 1088 + l15 * 68 + l4 * 16 + jj * 4];

    f32x4 hv = *(const f32x4*)&mem[(size_t)s * HDIM + jfirst];
    f32x4 o;
#pragma unroll
    for (int jj = 0; jj < 4; jj++) {
      const int j = jfirst + jj;
      f32x4 bt = *(const f32x4*)&btab[4 * j];
      float rr = fast_sigmoid(q[jj][0] + bt[0]);
      float zz = fast_sigmoid(q[jj][1] + bt[1]);
      float nn = fast_tanh(q[jj][2] + bt[2] + rr * (q[jj][3] + bt[3]));
      o[jj] = (1.0f - zz) * nn + zz * hv[jj];
    }
    if (wr) __builtin_nontemporal_store(o, (f32x4*)&out[(size_t)s * HDIM + jfirst]);
    __syncthreads();
  }
}

// ---------------- launch ----------------

extern "C" void kernel_launch(void* const* d_in, const int* in_sizes, int n_in,
                              void* d_out, int out_size, void* d_ws, size_t ws_size,
                              hipStream_t stream) {
  const float* mem = (const float*)d_in[0];
  const int*   sid = (const int*)d_in[1];
  const float* edu = (const float*)d_in[2];
  const float* Wih = (const float*)d_in[3];
  const float* Whh = (const float*)d_in[4];
  const float* bih = (const float*)d_in[5];
  const float* bhh = (const float*)d_in[6];
  float* out = (float*)d_out;

  char* p = (char*)d_ws;
  unsigned short* Ac = (unsigned short*)p; p += (size_t)TROWS * KDIM * 2;   // 32 MiB
  unsigned short* Bc = (unsigned short*)p; p += (size_t)NDIM * KDIM * 2;    // 16 MiB
  int*   lp   = (int*)p;   p += (size_t)SROWS * 4;                          // 256 KiB
  float* btab = (float*)p; p += (size_t)HDIM * 4 * 4;                       // 16 KiB
  unsigned long long* flagb = (unsigned long long*)p; p += (size_t)(SROWS / 64) * 8; // 8 KiB

  hipFuncSetAttribute((const void*)k_gru8, hipFuncAttributeMaxDynamicSharedMemorySize, 131072);

  hipLaunchKernelGGL(k_initlp, dim3(SROWS / 256), dim3(256), 0, stream, lp);
  hipLaunchKernelGGL(k_lp, dim3(TROWS / 256), dim3(256), 0, stream, sid, lp);
  hipLaunchKernelGGL(k_flags, dim3(SROWS / 256), dim3(256), 0, stream, lp, flagb);
  hipLaunchKernelGGL(k_bias, dim3(4), dim3(256), 0, stream, bih, bhh, btab);
  hipLaunchKernelGGL(k_build_A, dim3((TROWS * KDIM / 8) / 256), dim3(256), 0, stream, edu, mem, sid, Ac);
  hipLaunchKernelGGL(k_build_B, dim3((NDIM * KDIM / 8) / 256), dim3(256), 0, stream, Wih, Whh, Bc);
  hipLaunchKernelGGL(k_gru8, dim3(512), dim3(512), 131072, stream,
                     Ac, Bc, mem, sid, lp, flagb, btab, out);
}

// Round 6
// 241.583 us; speedup vs baseline: 1.5309x; 1.0220x over previous
//
#include <hip/hip_runtime.h>
#include <hip/hip_bf16.h>
#include <stdint.h>
#include <stddef.h>

typedef short short8 __attribute__((ext_vector_type(8)));
typedef float f32x4 __attribute__((ext_vector_type(4)));

#define SROWS 65536
#define TROWS 8192
#define HDIM  1024
#define KDIM  2048   // concatenated K: [edu | h]
#define NDIM  4096   // c = 4*j + gate
#define BK    32
#define NT2   (KDIM / BK)   // 64 K-tiles
#define NCOPY 128           // copy blocks (dispatched first)

__device__ __forceinline__ unsigned short f2bf(float f) {
  union { float f; uint32_t u; } v; v.f = f;
  uint32_t u = v.u;
  uint32_t r = (u + 0x7FFFu + ((u >> 16) & 1u)) >> 16;
  return (unsigned short)r;
}

__device__ __forceinline__ float fast_sigmoid(float x) {
  return __builtin_amdgcn_rcpf(1.0f + __builtin_amdgcn_exp2f(-1.44269504f * x));
}
__device__ __forceinline__ float fast_tanh(float x) {
  return 1.0f - 2.0f * __builtin_amdgcn_rcpf(1.0f + __builtin_amdgcn_exp2f(2.88539008f * x));
}

// ---------------- small prep kernels ----------------

__global__ __launch_bounds__(256) void k_initlp(int* lp) {
  int i = blockIdx.x * 256 + threadIdx.x;
  if (i < SROWS) lp[i] = -1;
}

__global__ __launch_bounds__(256) void k_lp(const int* __restrict__ sid, int* lp) {
  int i = blockIdx.x * 256 + threadIdx.x;
  if (i < TROWS) atomicMax(&lp[sid[i]], i);
}

// per-row "untouched" bitmask: bit r of flagb[r>>6] = (lp[r] < 0)
__global__ __launch_bounds__(256) void k_flags(const int* __restrict__ lp,
                                               unsigned long long* __restrict__ flagb) {
  int i = blockIdx.x * 256 + threadIdx.x;
  unsigned long long m = __ballot(lp[i] < 0);
  if ((threadIdx.x & 63) == 0) flagb[i >> 6] = m;
}

__global__ __launch_bounds__(256) void k_bias(const float* __restrict__ bih,
                                              const float* __restrict__ bhh,
                                              float* __restrict__ btab) {
  int j = blockIdx.x * 256 + threadIdx.x;
  if (j < HDIM) {
    btab[4*j+0] = bih[j] + bhh[j];
    btab[4*j+1] = bih[j+HDIM] + bhh[j+HDIM];
    btab[4*j+2] = bih[j+2*HDIM];
    btab[4*j+3] = bhh[j+2*HDIM];
  }
}

__global__ __launch_bounds__(256) void k_build_A(const float* __restrict__ edu,
                                                 const float* __restrict__ mem,
                                                 const int* __restrict__ sid,
                                                 unsigned short* __restrict__ Ac) {
  const int idx = blockIdx.x * 256 + threadIdx.x;
  const int t  = idx >> 8;
  const int k0 = (idx & 255) << 3;
  const float* src;
  if (k0 < HDIM) src = edu + (size_t)t * HDIM + k0;
  else           src = mem + (size_t)sid[t] * HDIM + (k0 - HDIM);
  f32x4 f0 = *(const f32x4*)src;
  f32x4 f1 = *(const f32x4*)(src + 4);
  short8 v;
  v[0]=(short)f2bf(f0[0]); v[1]=(short)f2bf(f0[1]); v[2]=(short)f2bf(f0[2]); v[3]=(short)f2bf(f0[3]);
  v[4]=(short)f2bf(f1[0]); v[5]=(short)f2bf(f1[1]); v[6]=(short)f2bf(f1[2]); v[7]=(short)f2bf(f1[3]);
  *(short8*)(Ac + (size_t)idx * 8) = v;
}

__global__ __launch_bounds__(256) void k_build_B(const float* __restrict__ Wih,
                                                 const float* __restrict__ Whh,
                                                 unsigned short* __restrict__ Bc) {
  const int idx = blockIdx.x * 256 + threadIdx.x;
  const int c  = idx >> 8;
  const int k0 = (idx & 255) << 3;
  const int j  = c >> 2;
  const int g  = c & 3;
  const float* src = nullptr;
  if (g == 0)      src = (k0 < HDIM) ? Wih + (size_t)j * HDIM + k0
                                     : Whh + (size_t)j * HDIM + (k0 - HDIM);
  else if (g == 1) src = (k0 < HDIM) ? Wih + (size_t)(j + HDIM) * HDIM + k0
                                     : Whh + (size_t)(j + HDIM) * HDIM + (k0 - HDIM);
  else if (g == 2) { if (k0 < HDIM)  src = Wih + (size_t)(j + 2*HDIM) * HDIM + k0; }
  else             { if (k0 >= HDIM) src = Whh + (size_t)(j + 2*HDIM) * HDIM + (k0 - HDIM); }
  short8 v = (short8)0;
  if (src) {
    f32x4 f0 = *(const f32x4*)src;
    f32x4 f1 = *(const f32x4*)(src + 4);
    v[0]=(short)f2bf(f0[0]); v[1]=(short)f2bf(f0[1]); v[2]=(short)f2bf(f0[2]); v[3]=(short)f2bf(f0[3]);
    v[4]=(short)f2bf(f1[0]); v[5]=(short)f2bf(f1[1]); v[6]=(short)f2bf(f1[2]); v[7]=(short)f2bf(f1[3]);
  }
  *(short8*)(Bc + (size_t)idx * 8) = v;
}

// ---------------- fused dispatch: copy blocks + GEMM blocks ----------------
// GEMM: BM=BN=256, BK=32, 8 waves (2M x 4N), 64 KiB dynamic LDS (dbuf A16K+B16K),
//   paired-row LDS lines (128B = 2 rows x 32k), XOR swizzle slot^=(line&7), both sides.
//   2 phases/K-tile, VM(0) per tile, setprio around MFMA.
// COPY: NCOPY barrier-free streaming blocks (SGPR flag bitmask, sw-pipelined nt ld/st)
//   co-resident with GEMM blocks on the same CU (64+64 KiB LDS, low VGPR).

#define FENCE() asm volatile("" ::: "memory")
#define BAR()   __builtin_amdgcn_s_barrier()
#define LGKM0() asm volatile("s_waitcnt lgkmcnt(0)" ::: "memory")
#define VM(N)   asm volatile("s_waitcnt vmcnt(" #N ")" ::: "memory")

#define STAGE2(p0, p1, ldsoff)                                                             \
  __builtin_amdgcn_global_load_lds((const __attribute__((address_space(1))) void*)(p0),   \
      (__attribute__((address_space(3))) void*)(smem + (ldsoff) + w * 2048), 16, 0, 0);    \
  __builtin_amdgcn_global_load_lds((const __attribute__((address_space(1))) void*)(p1),   \
      (__attribute__((address_space(3))) void*)(smem + (ldsoff) + w * 2048 + 1024), 16, 0, 0);

#define LDF(off) (*(const short8*)(smem + (off)))

__global__ __launch_bounds__(512, 2)
void k_fused(const unsigned short* __restrict__ Ac,
             const unsigned short* __restrict__ Bc,
             const float* __restrict__ mem,
             const int* __restrict__ sid,
             const int* __restrict__ lp,
             const unsigned long long* __restrict__ flagb,
             const float* __restrict__ btab,
             float* __restrict__ out) {
  extern __shared__ char smem[];
  const int bid = blockIdx.x;
  const int tid = threadIdx.x;

  // ================= copy blocks =================
  if (bid < NCOPY) {
    const int rbase = bid << 9;              // 512 rows per copy block
    unsigned long long fw[8];
#pragma unroll
    for (int i = 0; i < 8; i++) fw[i] = flagb[bid * 8 + i];
    const int half = tid >> 8;               // 0/1
    const int col  = (tid & 255) << 2;

    int ra = 0 + half, rb = 256 + half;
    bool va = (fw[ra >> 6] >> (ra & 63)) & 1ull;
    bool vb = (fw[rb >> 6] >> (rb & 63)) & 1ull;
    f32x4 da, db;
    if (va) da = __builtin_nontemporal_load((const f32x4*)&mem[(size_t)(rbase + ra) * HDIM + col]);
    if (vb) db = __builtin_nontemporal_load((const f32x4*)&mem[(size_t)(rbase + rb) * HDIM + col]);

    for (int r = 2; r < 256; r += 2) {
      const int ra2 = r + half, rb2 = 256 + r + half;
      const bool va2 = (fw[ra2 >> 6] >> (ra2 & 63)) & 1ull;
      const bool vb2 = (fw[rb2 >> 6] >> (rb2 & 63)) & 1ull;
      f32x4 da2, db2;
      if (va2) da2 = __builtin_nontemporal_load((const f32x4*)&mem[(size_t)(rbase + ra2) * HDIM + col]);
      if (vb2) db2 = __builtin_nontemporal_load((const f32x4*)&mem[(size_t)(rbase + rb2) * HDIM + col]);
      if (va) __builtin_nontemporal_store(da, (f32x4*)&out[(size_t)(rbase + ra) * HDIM + col]);
      if (vb) __builtin_nontemporal_store(db, (f32x4*)&out[(size_t)(rbase + rb) * HDIM + col]);
      va = va2; vb = vb2; da = da2; db = db2; ra = ra2; rb = rb2;
    }
    if (va) __builtin_nontemporal_store(da, (f32x4*)&out[(size_t)(rbase + ra) * HDIM + col]);
    if (vb) __builtin_nontemporal_store(db, (f32x4*)&out[(size_t)(rbase + rb) * HDIM + col]);
    return;
  }

  // ================= GEMM blocks =================
  const int g    = bid - NCOPY;
  const int lane = tid & 63;
  const int w    = tid >> 6;
  const int wm   = w >> 2;        // M half (0..1)
  const int wn   = w & 3;         // N quarter (0..3)
  const int l15  = lane & 15;
  const int l4   = lane >> 4;

  // XCD-aware swizzle (512 % 8 == 0 -> bijective; NCOPY%8==0 keeps bid%8 alignment)
  const int swz = (g & 7) * 64 + (g >> 3);
  const int t0  = (swz >> 4) * 256;
  const int c0  = (swz & 15) * 256;

  // ---- staging source mapping (inverse swizzle folded in) ----
  // phys line = w*16 + j*8 + (lane>>3), sp = lane&7; s_log = sp ^ (line&7) = sp ^ (lane>>3)
  // row = 2*line + (s_log>>2), kelem = (s_log&3)*8 ; j=1 -> row += 16
  const int slog  = (lane & 7) ^ (lane >> 3);
  const int row0  = 2 * (w * 16 + (lane >> 3)) + (slog >> 2);
  const int kelem = (slog & 3) * 8;

  const unsigned short* pA0 = Ac + (size_t)(t0 + row0) * KDIM + kelem;
  const unsigned short* pA1 = pA0 + (size_t)16 * KDIM;
  const unsigned short* pB0 = Bc + (size_t)(c0 + row0) * KDIM + kelem;
  const unsigned short* pB1 = pB0 + (size_t)16 * KDIM;

  // ---- fragment read offsets ----
  // row r -> line r>>1, half r&1 ; s_log = (r&1)*4 + l4 ; sp = s_log ^ (line&7)
  const int fsp   = ((l15 & 1) * 4 + l4) ^ ((l15 >> 1) & 7);
  const int afo   = (wm * 64 + (l15 >> 1)) * 128 + fsp * 16;   // + m*1024 + Abase
  const int bfo   = (wn * 32 + (l15 >> 1)) * 128 + fsp * 16;   // + n*1024 + Bbase

  f32x4 acc[8][4];
#pragma unroll
  for (int i = 0; i < 8; i++)
#pragma unroll
    for (int j = 0; j < 4; j++) acc[i][j] = (f32x4){0.f, 0.f, 0.f, 0.f};

  // ---- prologue: tile 0 into buf0
  STAGE2(pA0, pA1, 0);
  STAGE2(pB0, pB1, 16384);
  VM(0);
  FENCE(); BAR();

  for (int t = 0; t < NT2; ++t) {
    const int cur = t & 1, nxt = cur ^ 1;
    const int abase = cur * 32768;
    const int bbase = cur * 32768 + 16384;
    const int kt1 = (t + 1 < NT2) ? t + 1 : NT2 - 1;

    short8 af[4], bf[4];
#pragma unroll
    for (int n = 0; n < 4; n++) bf[n] = LDF(bbase + bfo + n * 1024);
#pragma unroll
    for (int m = 0; m < 4; m++) af[m] = LDF(abase + afo + m * 1024);

    STAGE2(pA0 + kt1 * BK, pA1 + kt1 * BK, nxt * 32768);
    STAGE2(pB0 + kt1 * BK, pB1 + kt1 * BK, nxt * 32768 + 16384);

    FENCE(); BAR();
    LGKM0();
    __builtin_amdgcn_s_setprio(1);
#pragma unroll
    for (int m = 0; m < 4; m++)
#pragma unroll
      for (int n = 0; n < 4; n++)
        acc[m][n] = __builtin_amdgcn_mfma_f32_16x16x32_bf16(af[m], bf[n], acc[m][n], 0, 0, 0);
    __builtin_amdgcn_s_setprio(0);

    // phase 1: m4..7 (reads cur only; no cross-wave hazard -> no barrier needed)
    short8 af2[4];
#pragma unroll
    for (int m = 0; m < 4; m++) af2[m] = LDF(abase + afo + (m + 4) * 1024);
    LGKM0();
    __builtin_amdgcn_s_setprio(1);
#pragma unroll
    for (int m = 0; m < 4; m++)
#pragma unroll
      for (int n = 0; n < 4; n++)
        acc[m + 4][n] = __builtin_amdgcn_mfma_f32_16x16x32_bf16(af2[m], bf[n], acc[m + 4][n], 0, 0, 0);
    __builtin_amdgcn_s_setprio(0);

    VM(0);               // next tile's A/B staged; safe to read nxt & overwrite cur
    FENCE(); BAR();
  }

  // ---- epilogue: LDS transpose per 16-row chunk, gates, guarded scatter
  __syncthreads();
  float* epi = (float*)smem;   // [8 waves][16][68]
  const int jfirst = ((c0 + wn * 64) >> 2) + l4 * 4;

#pragma unroll
  for (int mf = 0; mf < 8; mf++) {
#pragma unroll
    for (int nf = 0; nf < 4; nf++)
#pragma unroll
      for (int r = 0; r < 4; r++)
        epi[w * 1088 + (l4 * 4 + r) * 68 + nf * 16 + l15] = acc[mf][nf][r];
    __syncthreads();

    const int trow = t0 + wm * 128 + mf * 16 + l15;
    const int s    = sid[trow];
    const bool wr  = (lp[s] == trow);

    f32x4 q[4];
#pragma unroll
    for (int jj = 0; jj < 4; jj++)
      q[jj] = *(const f32x4*)&epi[w * 1088 + l15 * 68 + l4 * 16 + jj * 4];

    f32x4 hv = *(const f32x4*)&mem[(size_t)s * HDIM + jfirst];
    f32x4 o;
#pragma unroll
    for (int jj = 0; jj < 4; jj++) {
      const int j = jfirst + jj;
      f32x4 bt = *(const f32x4*)&btab[4 * j];
      float rr = fast_sigmoid(q[jj][0] + bt[0]);
      float zz = fast_sigmoid(q[jj][1] + bt[1]);
      float nn = fast_tanh(q[jj][2] + bt[2] + rr * (q[jj][3] + bt[3]));
      o[jj] = (1.0f - zz) * nn + zz * hv[jj];
    }
    if (wr) __builtin_nontemporal_store(o, (f32x4*)&out[(size_t)s * HDIM + jfirst]);
    __syncthreads();
  }
}

// ---------------- launch ----------------

extern "C" void kernel_launch(void* const* d_in, const int* in_sizes, int n_in,
                              void* d_out, int out_size, void* d_ws, size_t ws_size,
                              hipStream_t stream) {
  const float* mem = (const float*)d_in[0];
  const int*   sid = (const int*)d_in[1];
  const float* edu = (const float*)d_in[2];
  const float* Wih = (const float*)d_in[3];
  const float* Whh = (const float*)d_in[4];
  const float* bih = (const float*)d_in[5];
  const float* bhh = (const float*)d_in[6];
  float* out = (float*)d_out;

  char* p = (char*)d_ws;
  unsigned short* Ac = (unsigned short*)p; p += (size_t)TROWS * KDIM * 2;   // 32 MiB
  unsigned short* Bc = (unsigned short*)p; p += (size_t)NDIM * KDIM * 2;    // 16 MiB
  int*   lp   = (int*)p;   p += (size_t)SROWS * 4;                          // 256 KiB
  float* btab = (float*)p; p += (size_t)HDIM * 4 * 4;                       // 16 KiB
  unsigned long long* flagb = (unsigned long long*)p; p += (size_t)(SROWS / 64) * 8; // 8 KiB

  hipFuncSetAttribute((const void*)k_fused, hipFuncAttributeMaxDynamicSharedMemorySize, 65536);

  hipLaunchKernelGGL(k_initlp, dim3(SROWS / 256), dim3(256), 0, stream, lp);
  hipLaunchKernelGGL(k_lp, dim3(TROWS / 256), dim3(256), 0, stream, sid, lp);
  hipLaunchKernelGGL(k_flags, dim3(SROWS / 256), dim3(256), 0, stream, lp, flagb);
  hipLaunchKernelGGL(k_bias, dim3(4), dim3(256), 0, stream, bih, bhh, btab);
  hipLaunchKernelGGL(k_build_A, dim3((TROWS * KDIM / 8) / 256), dim3(256), 0, stream, edu, mem, sid, Ac);
  hipLaunchKernelGGL(k_build_B, dim3((NDIM * KDIM / 8) / 256), dim3(256), 0, stream, Wih, Whh, Bc);
  hipLaunchKernelGGL(k_fused, dim3(NCOPY + 512), dim3(512), 65536, stream,
                     Ac, Bc, mem, sid, lp, flagb, btab, out);
}